// Round 15
// baseline (1968.976 us; speedup 1.0000x reference)
//
#include <hip/hip_runtime.h>

typedef _Float16 h2 __attribute__((ext_vector_type(2)));
typedef _Float16 h4 __attribute__((ext_vector_type(4)));

#define NN 256
#define SS 1000
#define DD 64
#define HH 256
#define ZZ 128
#define HIDN 256

__device__ __forceinline__ float fdot2(h2 a, h2 b, float c) {
  return __builtin_amdgcn_fdot2(a, b, c, false);
}
__device__ __forceinline__ float fast_tanh(float x) {
  float e = __expf(2.0f * x);
  return 1.0f - 2.0f / (e + 1.0f);
}
__device__ __forceinline__ float elu1(float x) {
  return x > 0.0f ? x : (__expf(x) - 1.0f);
}
__device__ __forceinline__ h2 pack2(float a, float b) {
  h2 r; r.x = (_Float16)a; r.y = (_Float16)b; return r;
}
__device__ __forceinline__ void u4c(uint4 u, h2* c) {
  c[0] = __builtin_bit_cast(h2, u.x);
  c[1] = __builtin_bit_cast(h2, u.y);
  c[2] = __builtin_bit_cast(h2, u.z);
  c[3] = __builtin_bit_cast(h2, u.w);
}
// DPP cross-lane adds (numerics proven identical to shfl_xor in r5/r6).
template <int CTRL>
__device__ __forceinline__ float dppadd(float a) {
  int x = __builtin_bit_cast(int, a);
  int y = __builtin_amdgcn_update_dpp(0, x, CTRL, 0xf, 0xf, true);
  return a + __builtin_bit_cast(float, y);
}
__device__ __forceinline__ float red4(float a) {
  a = dppadd<0xB1>(a); a = dppadd<0x4E>(a); return a;
}
__device__ __forceinline__ float red8(float a) {
  a = dppadd<0x141>(a); a = dppadd<0x4E>(a); a = dppadd<0xB1>(a); return a;
}
__device__ __forceinline__ float red16(float a) {
  a = dppadd<0x140>(a); a = dppadd<0x141>(a); a = dppadd<0x4E>(a);
  a = dppadd<0xB1>(a); return a;
}
// padded f16 index for 32-wide/80B slices (epilogue scalar reads)
__device__ __forceinline__ int HIX(int j) { return (j >> 5) * 40 + (j & 31); }

// ---------------- Kernel 1: reverse RNN + encoder -> z0 ----------------
// 1024 threads (k_ode-proven geometry): group q8=t>>3 owns rows {2q8,2q8+1},
// lane e8=t&7 owns input-eighth. h in 80B-padded slices (conflict-free),
// x in 32B-padded slices (2-way = free). red8 mirror reduction (r8-proven).
__global__ __launch_bounds__(1024, 1) void k_rnn(
    const float* __restrict__ X, const float* __restrict__ Wih,
    const float* __restrict__ Whh, const float* __restrict__ bih,
    const float* __restrict__ bhh, const float* __restrict__ Wcomp,
    const float* __restrict__ bcomp, const float* __restrict__ eps,
    const float* __restrict__ Wrc, const float* __restrict__ brc,
    float* __restrict__ z0out) {
  const int n = blockIdx.x;
  const int t = threadIdx.x;
  const int q8 = t >> 3, e8 = t & 7;
  __shared__ __align__(16) _Float16 hb[2][8 * 40];  // 8 x (32 f16 + 8 pad)
  __shared__ __align__(16) _Float16 xb[2][8 * 16];  // 8 x (8 f16 + 8 pad)
  __shared__ float comp_s[HH];
  __shared__ float zenc_s[ZZ];

  h2 wih2[2][4];   // rows {2q8,2q8+1} x cols 8e8..8e8+7
  h2 whh2[2][16];  // rows {2q8,2q8+1} x cols 32e8..32e8+31
  float bi2[2];
#pragma unroll
  for (int i = 0; i < 2; ++i) {
    const float4* wp = (const float4*)(Wih + (2 * q8 + i) * DD + 8 * e8);
#pragma unroll
    for (int j4 = 0; j4 < 2; ++j4) {
      float4 v = wp[j4];
      wih2[i][2 * j4] = pack2(v.x, v.y);
      wih2[i][2 * j4 + 1] = pack2(v.z, v.w);
    }
    const float4* hp = (const float4*)(Whh + (2 * q8 + i) * HH + 32 * e8);
#pragma unroll
    for (int j4 = 0; j4 < 8; ++j4) {
      float4 v = hp[j4];
      whh2[i][2 * j4] = pack2(v.x, v.y);
      whh2[i][2 * j4 + 1] = pack2(v.z, v.w);
    }
    bi2[i] = bih[2 * q8 + i] + bhh[2 * q8 + i];
  }
  if (t < 320) hb[0][t] = (_Float16)0.0f;
  if (t < 32) {
    const float2 v = ((const float2*)(X + ((size_t)n * SS + (SS - 1)) * DD))[t];
    *(h2*)((char*)xb[0] + (t >> 2) * 32 + (t & 3) * 4) = pack2(v.x, v.y);
  }
  // hoisted write address for h (same pattern as k_ode's h1wr)
  char* hwr0 = (char*)hb[0] + ((2 * q8) >> 5) * 80 + ((2 * q8) & 31) * 2;
  char* hwr1 = (char*)hb[1] + ((2 * q8) >> 5) * 80 + ((2 * q8) & 31) * 2;
  int cur = 0;
#pragma unroll 1
  for (int s = 0; s < SS; ++s) {
    __syncthreads();  // xb[cur], hb[cur] ready
    float2 xv = {0.f, 0.f};
    const bool pf = (t < 32) && (s + 1 < SS);
    if (pf)
      xv = ((const float2*)(X + ((size_t)n * SS + (SS - 2 - s)) * DD))[t];
    h2 cx[4];   // x eighth: 8 f16
    h2 ch[16];  // h eighth: 32 f16
    {
      uint4 ux = *(const uint4*)((const char*)xb[cur] + e8 * 32);
      u4c(ux, cx);
      const uint4* hq = (const uint4*)((const char*)hb[cur] + e8 * 80);
      uint4 u0 = hq[0], u1 = hq[1], u2 = hq[2], u3 = hq[3];
      u4c(u0, ch); u4c(u1, ch + 4); u4c(u2, ch + 8); u4c(u3, ch + 12);
    }
    float a0 = 0.f, a1 = 0.f;
#pragma unroll
    for (int j = 0; j < 4; ++j) {
      a0 = fdot2(wih2[0][j], cx[j], a0);
      a1 = fdot2(wih2[1][j], cx[j], a1);
    }
#pragma unroll
    for (int j = 0; j < 16; ++j) {
      a0 = fdot2(whh2[0][j], ch[j], a0);
      a1 = fdot2(whh2[1][j], ch[j], a1);
    }
    a0 = red8(a0);
    a1 = red8(a1);
    if (e8 == 0)
      *(h2*)(cur ? hwr0 : hwr1) =
          pack2(fast_tanh(a0 + bi2[0]), fast_tanh(a1 + bi2[1]));
    if (pf)
      *(h2*)((char*)xb[cur ^ 1] + (t >> 2) * 32 + (t & 3) * 4) =
          pack2(xv.x, xv.y);
    cur ^= 1;
  }
  __syncthreads();
  // ---- encoder epilogue (one-time; t<512 guards, padded h reads) ----
  const int r2 = t >> 1, c2 = t & 1;
  if (t < 512) {
    float a = c2 ? 0.0f : bcomp[r2];
    const float4* wc = (const float4*)(Wcomp + r2 * HH + c2 * 128);
#pragma unroll 8
    for (int j = 0; j < 32; ++j) {
      float4 w = wc[j];
      a += w.x * (float)hb[cur][HIX(c2 * 128 + 4 * j + 0)] +
           w.y * (float)hb[cur][HIX(c2 * 128 + 4 * j + 1)] +
           w.z * (float)hb[cur][HIX(c2 * 128 + 4 * j + 2)] +
           w.w * (float)hb[cur][HIX(c2 * 128 + 4 * j + 3)];
    }
    a += __shfl_xor(a, 1);
    if (!c2) comp_s[r2] = a;
  }
  __syncthreads();
  if (t < ZZ) {
    float mu = comp_s[t];
    float sd = comp_s[t + ZZ];
    zenc_s[t] = eps[(size_t)n * ZZ + t] * sd + mu;
  }
  __syncthreads();
  if (t < 512) {
    const int r4 = t >> 2, c4 = t & 3;
    float a = c4 ? 0.0f : brc[r4];
    const float4* wr = (const float4*)(Wrc + r4 * ZZ + c4 * 32);
    const float* zl = zenc_s + c4 * 32;
#pragma unroll
    for (int j = 0; j < 8; ++j) {
      float4 w = wr[j];
      a += w.x * zl[4 * j + 0] + w.y * zl[4 * j + 1] + w.z * zl[4 * j + 2] +
           w.w * zl[4 * j + 3];
    }
    a += __shfl_xor(a, 1);
    a += __shfl_xor(a, 2);
    if (!c4) z0out[(size_t)n * ZZ + r4] = a;
  }
}

// ------- Kernel 2: ODE, 1024 threads, RK2 with H = 4dt -------------------
// (byte-identical to the passing round-14 version)
#define OFF_WD1 0        // 256x128 f16 = 65536
#define OFF_WD2 65536    // 64x256 f16  = 32768
#define OFF_DTS 98304    // 249 f32 -> 4096
#define OFF_ZP 102400    // 8 slices x 48B = 384
#define OFF_H1P 102784   // 8 slices x 80B = 640
#define OFF_H2P 103424   // 8 slices x 80B = 640
#define OFF_HDP 104064   // 8 slices x 80B = 640
#define OFF_ZP2 104704   // 8 slices x 48B = 384
#define OFF_HDP2 105088  // 8 slices x 80B = 640
#define SMEM_BYTES 105728

__global__ __launch_bounds__(1024, 1) void k_ode(
    const float* __restrict__ tarr, const float* __restrict__ z0in,
    const float* __restrict__ Wo1, const float* __restrict__ bo1p,
    const float* __restrict__ Wo2, const float* __restrict__ bo2p,
    const float* __restrict__ Wo3, const float* __restrict__ bo3p,
    const float* __restrict__ Wd1, const float* __restrict__ bd1p,
    const float* __restrict__ Wd2, const float* __restrict__ bd2p,
    float* __restrict__ out) {
  extern __shared__ char smem[];
  _Float16* wd1s = (_Float16*)(smem + OFF_WD1);
  _Float16* wd2s = (_Float16*)(smem + OFF_WD2);
  float* dts = (float*)(smem + OFF_DTS);
  _Float16* zp = (_Float16*)(smem + OFF_ZP);
  _Float16* h1p = (_Float16*)(smem + OFF_H1P);
  _Float16* h2p = (_Float16*)(smem + OFF_H2P);
  _Float16* hdp = (_Float16*)(smem + OFF_HDP);
  _Float16* zp2 = (_Float16*)(smem + OFF_ZP2);
  _Float16* hdp2 = (_Float16*)(smem + OFF_HDP2);

  const int n = blockIdx.x;
  const int t = threadIdx.x;
  const int q8 = t >> 3, e8 = t & 7;
  const int g16 = t >> 4, s16 = t & 15;

  h2 wL1[2][8];   // Wo1 rows {2q8,2q8+1} x cols 16e8..16e8+15
  h2 wL2[2][16];  // Wo2 rows {2q8,2q8+1} x cols 32e8..32e8+31
  h2 wL3[16];     // Wo3 row q8 x cols 32e8..32e8+31
  float bo1r[2], bo2r[2], bd1r[2];
#pragma unroll
  for (int i = 0; i < 2; ++i) {
    const float4* p1 = (const float4*)(Wo1 + (2 * q8 + i) * ZZ + 16 * e8);
#pragma unroll
    for (int j4 = 0; j4 < 4; ++j4) {
      float4 v = p1[j4];
      wL1[i][2 * j4] = pack2(v.x, v.y);
      wL1[i][2 * j4 + 1] = pack2(v.z, v.w);
    }
    const float4* p2 = (const float4*)(Wo2 + (2 * q8 + i) * HIDN + 32 * e8);
#pragma unroll
    for (int j4 = 0; j4 < 8; ++j4) {
      float4 v = p2[j4];
      wL2[i][2 * j4] = pack2(v.x, v.y);
      wL2[i][2 * j4 + 1] = pack2(v.z, v.w);
    }
    bo1r[i] = bo1p[2 * q8 + i];
    bo2r[i] = bo2p[2 * q8 + i];
    bd1r[i] = bd1p[2 * q8 + i];
  }
  {
    const float4* p3 = (const float4*)(Wo3 + q8 * HIDN + 32 * e8);
#pragma unroll
    for (int j4 = 0; j4 < 8; ++j4) {
      float4 v = p3[j4];
      wL3[2 * j4] = pack2(v.x, v.y);
      wL3[2 * j4 + 1] = pack2(v.z, v.w);
    }
  }
  const float bo3r = bo3p[q8];
  const float bd2r = bd2p[g16];

  // stage decoder weights (f16) + quad-step dt table to LDS
#pragma unroll 1
  for (int idx = t; idx < HIDN * ZZ; idx += 1024)
    wd1s[idx] = (_Float16)Wd1[idx];
#pragma unroll 1
  for (int idx = t; idx < DD * HIDN; idx += 1024)
    wd2s[idx] = (_Float16)Wd2[idx];
#pragma unroll 1
  for (int idx = t; idx < (SS - 4) / 4 + 1; idx += 1024)
    dts[idx] = tarr[4 * idx + 4] - tarr[4 * idx];  // H = 4*dt, j = 0..248
  const float dt2 = tarr[SS - 2] - tarr[SS - 4];   // 996 -> 998
  const float dtt = tarr[SS - 1] - tarr[SS - 2];   // 998 -> 999

  // z state: row q8 (1:1 group<->row), replicated across the 8 e8 lanes
  float zv = z0in[(size_t)n * ZZ + q8];
  if (t < 32) {
    const float4 zl = *(const float4*)(z0in + (size_t)n * ZZ + 4 * t);
    h4 pk;
    pk[0] = (_Float16)zl.x; pk[1] = (_Float16)zl.y;
    pk[2] = (_Float16)zl.z; pk[3] = (_Float16)zl.w;
    *(h4*)((char*)zp + (t >> 2) * 48 + (t & 3) * 8) = pk;
  }

  // hoisted LDS addresses
  const char* zrd = (const char*)zp + e8 * 48;
  const char* zrd2 = (const char*)zp2 + e8 * 48;
  const char* h1rd = (const char*)h1p + e8 * 80;
  const char* h2rd = (const char*)h2p + e8 * 80;
  const char* hdrd = (const char*)hdp + (s16 >> 1) * 80 + (s16 & 1) * 32;
  const char* hdrd2 = (const char*)hdp2 + (s16 >> 1) * 80 + (s16 & 1) * 32;
  char* h1wr = (char*)h1p + ((2 * q8) >> 5) * 80 + ((2 * q8) & 31) * 2;
  char* h2wr = (char*)h2p + ((2 * q8) >> 5) * 80 + ((2 * q8) & 31) * 2;
  char* hdwr = (char*)hdp + ((2 * q8) >> 5) * 80 + ((2 * q8) & 31) * 2;
  char* hdwr2 = (char*)hdp2 + ((2 * q8) >> 5) * 80 + ((2 * q8) & 31) * 2;
  _Float16* zwr = (_Float16*)((char*)zp + (q8 >> 4) * 48) + (q8 & 15);
  _Float16* zwr2 = (_Float16*)((char*)zp2 + (q8 >> 4) * 48) + (q8 & 15);
  const _Float16* wd1r = wd1s + (2 * q8) * ZZ + 16 * e8;
  const _Float16* wd2r = wd2s + g16 * HIDN + 16 * s16;

  // D1: decoder layer 1 from a z fragment, writing the given hd buffer
  auto D1w = [&](const h2* cz, char* hw) {
    h2 w0[8], w1[8];
    {
      const uint4* p0 = (const uint4*)wd1r;
      u4c(p0[0], w0); u4c(p0[1], w0 + 4);
      const uint4* p1 = (const uint4*)(wd1r + ZZ);
      u4c(p1[0], w1); u4c(p1[1], w1 + 4);
    }
    float a0 = 0.f, a1 = 0.f;
#pragma unroll
    for (int j = 0; j < 8; ++j) {
      a0 = fdot2(w0[j], cz[j], a0);
      a1 = fdot2(w1[j], cz[j], a1);
    }
    a0 = red8(a0);
    a1 = red8(a1);
    if (e8 == 0) {
      float v0 = a0 + bd1r[0], v1 = a1 + bd1r[1];
      v0 = v0 > 0.f ? v0 : 0.f;
      v1 = v1 > 0.f ? v1 : 0.f;
      *(h2*)hw = pack2(v0, v1);
    }
  };
  // D2: decoder layer 2 from the given hd buffer -> f32 out (proven path)
  auto D2r = [&](int sidx, const char* hr) {
    h2 w[8], hh[8];
    {
      const uint4* pw = (const uint4*)wd2r;
      u4c(pw[0], w); u4c(pw[1], w + 4);
      const uint4* ph = (const uint4*)hr;
      u4c(ph[0], hh); u4c(ph[1], hh + 4);
    }
    float a = 0.f;
#pragma unroll
    for (int j = 0; j < 8; ++j) a = fdot2(w[j], hh[j], a);
    a = red16(a);
    if (s16 == 0) out[((size_t)n * SS + sidx) * DD + g16] = a + bd2r;
  };
  auto load_z = [&](h2* cz, const char* base) {
    const uint4* zq = (const uint4*)base;
    uint4 u0 = zq[0], u1 = zq[1];
    u4c(u0, cz); u4c(u1, cz + 4);
  };

  // standalone decode (used for sidx=0 and sidx=SS-1)
  auto decode_standalone = [&](int sidx) {
    __syncthreads();
    h2 cz[8];
    load_z(cz, zrd);
    D1w(cz, hdwr);
    __syncthreads();
    D2r(sidx, hdrd);
  };

  // One RK2 double-stage with up to 2 folded decodes per sub-stage.
  // st0: k1 at z; writes zp<-zmid, zp2<-z+(H/4)k1 (if wAux).
  // st1: k2 at zmid; z += H*k2; writes zp<-z, zp2<-z_old+(3H/4)k2 (if wAux).
  auto two_stage = [&](float Hv, bool m0, int sm0, bool a0x, int sa0,
                       bool m1, int sm1, bool a1x, int sa1, bool wAux) {
#pragma unroll
    for (int st = 0; st < 2; ++st) {
      const bool dM = st ? m1 : m0;
      const bool dA = st ? a1x : a0x;
      const int sM = st ? sm1 : sm0;
      const int sA = st ? sa1 : sa0;
      __syncthreads();  // zp/zp2 (and prior-phase buffers) ready
      // ---- phase A: L1 (+ folded D1 main/aux) ----
      {
        h2 cz[8];
        load_z(cz, zrd);
        if (dM) D1w(cz, hdwr);
        if (dA) {
          h2 cz2[8];
          load_z(cz2, zrd2);
          D1w(cz2, hdwr2);
        }
        float a0 = 0.f, a1 = 0.f;
#pragma unroll
        for (int j = 0; j < 8; ++j) {
          a0 = fdot2(wL1[0][j], cz[j], a0);
          a1 = fdot2(wL1[1][j], cz[j], a1);
        }
        a0 = red8(a0);
        a1 = red8(a1);
        if (e8 == 0)
          *(h2*)h1wr = pack2(elu1(a0 + bo1r[0]), elu1(a1 + bo1r[1]));
      }
      __syncthreads();
      // ---- phase B: L2 (+ folded D2 main/aux) ----
      {
        if (dM) D2r(sM, hdrd);
        if (dA) D2r(sA, hdrd2);
        h2 ch[16];
        const uint4* hq = (const uint4*)h1rd;
        uint4 u0 = hq[0], u1 = hq[1], u2 = hq[2], u3 = hq[3];
        u4c(u0, ch); u4c(u1, ch + 4); u4c(u2, ch + 8); u4c(u3, ch + 12);
        float a0 = 0.f, a1 = 0.f;
#pragma unroll
        for (int j = 0; j < 16; ++j) {
          a0 = fdot2(wL2[0][j], ch[j], a0);
          a1 = fdot2(wL2[1][j], ch[j], a1);
        }
        a0 = red8(a0);
        a1 = red8(a1);
        if (e8 == 0)
          *(h2*)h2wr = pack2(elu1(a0 + bo2r[0]), elu1(a1 + bo2r[1]));
      }
      __syncthreads();
      // ---- phase C: L3 + RK2 update (row q8) ----
      {
        h2 ch[16];
        const uint4* hq = (const uint4*)h2rd;
        uint4 u0 = hq[0], u1 = hq[1], u2 = hq[2], u3 = hq[3];
        u4c(u0, ch); u4c(u1, ch + 4); u4c(u2, ch + 8); u4c(u3, ch + 12);
        float a = 0.f;
#pragma unroll
        for (int j = 0; j < 16; ++j) a = fdot2(wL3[j], ch[j], a);
        a = red8(a);
        const float f = a + bo3r;  // valid in all 8 lanes of the group
        float zc, za;
        if (st == 0) {
          zc = zv + 0.5f * Hv * f;   // zmid = z + (H/2)*k1
          za = zv + 0.25f * Hv * f;  // est pos +1
        } else {
          const float zo = zv;
          zv += Hv * f;  // z += H*k2
          zc = zv;
          za = zo + 0.75f * Hv * f;  // est pos +3 (consumed next stage)
        }
        if (e8 == 0) {
          *zwr = (_Float16)zc;
          if (wAux) *zwr2 = (_Float16)za;
        }
      }
    }
  };

  __syncthreads();  // dts, zp, wd1s/wd2s staged
  decode_standalone(0);

#pragma unroll 1
  for (int j = 0; j < 249; ++j) {
    // st0: main=pos 4j (j>0), aux=pos 4j-1 (j>0, from zp2 of prev stage)
    // st1: main=pos 4j+2 (zmid), aux=pos 4j+1 (zp2 = z+(H/4)k1)
    two_stage(dts[j], j > 0, 4 * j, j > 0, 4 * j - 1, true, 4 * j + 2, true,
              4 * j + 1, true);
  }
  // z = z_996; zp2 holds est of pos 995.
  // H=2dt step 996->998: st0 decodes 996(main)+995(aux); st1 decodes 997
  // from the true midpoint.
  two_stage(dt2, true, SS - 4, true, SS - 5, true, SS - 3, false, 0, false);
  // H=dt step 998->999: st0 decodes 998.
  two_stage(dtt, true, SS - 2, false, 0, false, 0, false, 0, false);
  decode_standalone(SS - 1);
}

extern "C" void kernel_launch(void* const* d_in, const int* in_sizes, int n_in,
                              void* d_out, int out_size, void* d_ws,
                              size_t ws_size, hipStream_t stream) {
  const float* X = (const float*)d_in[0];
  const float* tarr = (const float*)d_in[1];
  const float* eps = (const float*)d_in[2];
  const float* Wih = (const float*)d_in[3];
  const float* Whh = (const float*)d_in[4];
  const float* bih = (const float*)d_in[5];
  const float* bhh = (const float*)d_in[6];
  const float* Wcomp = (const float*)d_in[7];
  const float* bcomp = (const float*)d_in[8];
  const float* Wrc = (const float*)d_in[9];
  const float* brc = (const float*)d_in[10];
  const float* Wo1 = (const float*)d_in[11];
  const float* bo1 = (const float*)d_in[12];
  const float* Wo2 = (const float*)d_in[13];
  const float* bo2 = (const float*)d_in[14];
  const float* Wo3 = (const float*)d_in[15];
  const float* bo3 = (const float*)d_in[16];
  const float* Wd1 = (const float*)d_in[17];
  const float* bd1 = (const float*)d_in[18];
  const float* Wd2 = (const float*)d_in[19];
  const float* bd2 = (const float*)d_in[20];
  float* out = (float*)d_out;
  float* z0ws = (float*)d_ws;  // 256*128 f32 = 128 KiB

  k_rnn<<<dim3(NN), dim3(1024), 0, stream>>>(X, Wih, Whh, bih, bhh, Wcomp,
                                             bcomp, eps, Wrc, brc, z0ws);
  k_ode<<<dim3(NN), dim3(1024), SMEM_BYTES, stream>>>(
      tarr, z0ws, Wo1, bo1, Wo2, bo2, Wo3, bo3, Wd1, bd1, Wd2, bd2, out);
}

// Round 16
// 1889.962 us; speedup vs baseline: 1.0418x; 1.0418x over previous
//
#include <hip/hip_runtime.h>

typedef _Float16 h2 __attribute__((ext_vector_type(2)));
typedef _Float16 h4 __attribute__((ext_vector_type(4)));

#define NN 256
#define SS 1000
#define DD 64
#define HH 256
#define ZZ 128
#define HIDN 256

__device__ __forceinline__ float fdot2(h2 a, h2 b, float c) {
  return __builtin_amdgcn_fdot2(a, b, c, false);
}
__device__ __forceinline__ float fast_tanh(float x) {
  float e = __expf(2.0f * x);
  return 1.0f - 2.0f / (e + 1.0f);
}
__device__ __forceinline__ float elu1(float x) {
  return x > 0.0f ? x : (__expf(x) - 1.0f);
}
__device__ __forceinline__ h2 pack2(float a, float b) {
  h2 r; r.x = (_Float16)a; r.y = (_Float16)b; return r;
}
__device__ __forceinline__ void u4c(uint4 u, h2* c) {
  c[0] = __builtin_bit_cast(h2, u.x);
  c[1] = __builtin_bit_cast(h2, u.y);
  c[2] = __builtin_bit_cast(h2, u.z);
  c[3] = __builtin_bit_cast(h2, u.w);
}
// DPP cross-lane adds (numerics proven identical to shfl_xor in r5/r6).
template <int CTRL>
__device__ __forceinline__ float dppadd(float a) {
  int x = __builtin_bit_cast(int, a);
  int y = __builtin_amdgcn_update_dpp(0, x, CTRL, 0xf, 0xf, true);
  return a + __builtin_bit_cast(float, y);
}
__device__ __forceinline__ float red4(float a) {
  a = dppadd<0xB1>(a); a = dppadd<0x4E>(a); return a;
}
__device__ __forceinline__ float red8(float a) {
  a = dppadd<0x141>(a); a = dppadd<0x4E>(a); a = dppadd<0xB1>(a); return a;
}
__device__ __forceinline__ float red16(float a) {
  a = dppadd<0x140>(a); a = dppadd<0x141>(a); a = dppadd<0x4E>(a);
  a = dppadd<0xB1>(a); return a;
}

// ---------------- Kernel 1: reverse RNN + encoder -> z0 ----------------
// r14-proven 512-thread quad-split; x staged in 16-step LDS chunks so the
// global load (and its vmcnt-drain at the barrier) hits 1 step in 16.
__global__ __launch_bounds__(512, 2) void k_rnn(
    const float* __restrict__ X, const float* __restrict__ Wih,
    const float* __restrict__ Whh, const float* __restrict__ bih,
    const float* __restrict__ bhh, const float* __restrict__ Wcomp,
    const float* __restrict__ bcomp, const float* __restrict__ eps,
    const float* __restrict__ Wrc, const float* __restrict__ brc,
    float* __restrict__ z0out) {
  const int n = blockIdx.x;
  const int t = threadIdx.x;
  const int g = t >> 2, c = t & 3;
  __shared__ __align__(16) _Float16 hb[2][HH];       // contiguous h state
  __shared__ __align__(16) _Float16 xc[2][16][DD];   // 2 x 16-step x chunks
  __shared__ float comp_s[HH];
  __shared__ float zenc_s[ZZ];

  h2 wih2[2][8];   // rows {2g,2g+1} x cols 16c..16c+15
  h2 whh2[2][32];  // rows {2g,2g+1} x cols 64c..64c+63
  float bi2[2];
#pragma unroll
  for (int i = 0; i < 2; ++i) {
    const float4* wp = (const float4*)(Wih + (2 * g + i) * DD + 16 * c);
#pragma unroll
    for (int j4 = 0; j4 < 4; ++j4) {
      float4 v = wp[j4];
      wih2[i][2 * j4] = pack2(v.x, v.y);
      wih2[i][2 * j4 + 1] = pack2(v.z, v.w);
    }
    const float4* hp = (const float4*)(Whh + (2 * g + i) * HH + 64 * c);
#pragma unroll
    for (int j4 = 0; j4 < 16; ++j4) {
      float4 v = hp[j4];
      whh2[i][2 * j4] = pack2(v.x, v.y);
      whh2[i][2 * j4 + 1] = pack2(v.z, v.w);
    }
    bi2[i] = bih[2 * g + i] + bhh[2 * g + i];
  }
  // stage chunk cn (steps 16cn..16cn+15): 512 thr x float2 = 16 rows x 64
  auto stage = [&](int cn) {
    const int row = t >> 5;          // 0..15
    const int sp = 16 * cn + row;    // step index
    if (sp < SS) {
      const float2 v =
          ((const float2*)(X + ((size_t)n * SS + (SS - 1 - sp)) * DD))[t & 31];
      *(h2*)(&xc[cn & 1][row][(t & 31) * 2]) = pack2(v.x, v.y);
    }
  };
  if (t < HH) hb[0][t] = (_Float16)0.0f;
  stage(0);
  int cur = 0;
#pragma unroll 1
  for (int s = 0; s < SS; ++s) {
    __syncthreads();  // xc chunk, hb[cur] ready
    if ((s & 15) == 0) {
      const int cn = (s >> 4) + 1;
      if (16 * cn < SS) stage(cn);  // prefetch next chunk (other buffer)
    }
    h2 cx[8];   // x quarter: 16 f16
    h2 ch[32];  // h quarter: 64 f16
    {
      const uint4* xq = (const uint4*)(&xc[(s >> 4) & 1][s & 15][16 * c]);
      u4c(xq[0], cx);
      u4c(xq[1], cx + 4);
      const uint4* hq = (const uint4*)(hb[cur] + 64 * c);
#pragma unroll
      for (int j4 = 0; j4 < 8; ++j4) u4c(hq[j4], ch + 4 * j4);
    }
    float a0 = 0.f, a1 = 0.f;
#pragma unroll
    for (int j = 0; j < 8; ++j) {
      a0 = fdot2(wih2[0][j], cx[j], a0);
      a1 = fdot2(wih2[1][j], cx[j], a1);
    }
#pragma unroll
    for (int j = 0; j < 32; ++j) {
      a0 = fdot2(whh2[0][j], ch[j], a0);
      a1 = fdot2(whh2[1][j], ch[j], a1);
    }
    a0 = red4(a0);
    a1 = red4(a1);
    if (c == 0)
      ((h2*)hb[cur ^ 1])[g] =
          pack2(fast_tanh(a0 + bi2[0]), fast_tanh(a1 + bi2[1]));
    cur ^= 1;
  }
  __syncthreads();
  // ---- encoder epilogue (one-time; r14-proven) ----
  const int r2 = t >> 1, c2 = t & 1;
  {
    float a = c2 ? 0.0f : bcomp[r2];
    const float4* wc = (const float4*)(Wcomp + r2 * HH + c2 * 128);
#pragma unroll 8
    for (int j = 0; j < 32; ++j) {
      float4 w = wc[j];
      a += w.x * (float)hb[cur][c2 * 128 + 4 * j + 0] +
           w.y * (float)hb[cur][c2 * 128 + 4 * j + 1] +
           w.z * (float)hb[cur][c2 * 128 + 4 * j + 2] +
           w.w * (float)hb[cur][c2 * 128 + 4 * j + 3];
    }
    a += __shfl_xor(a, 1);
    if (!c2) comp_s[r2] = a;
  }
  __syncthreads();
  if (t < ZZ) {
    float mu = comp_s[t];
    float sd = comp_s[t + ZZ];
    zenc_s[t] = eps[(size_t)n * ZZ + t] * sd + mu;
  }
  __syncthreads();
  {
    const int r4 = t >> 2, c4 = t & 3;
    float a = c4 ? 0.0f : brc[r4];
    const float4* wr = (const float4*)(Wrc + r4 * ZZ + c4 * 32);
    const float* zl = zenc_s + c4 * 32;
#pragma unroll
    for (int j = 0; j < 8; ++j) {
      float4 w = wr[j];
      a += w.x * zl[4 * j + 0] + w.y * zl[4 * j + 1] + w.z * zl[4 * j + 2] +
           w.w * zl[4 * j + 3];
    }
    a += __shfl_xor(a, 1);
    a += __shfl_xor(a, 2);
    if (!c4) z0out[(size_t)n * ZZ + r4] = a;
  }
}

// ------- Kernel 2: ODE, 1024 threads, RK2 with H = 4dt -------------------
// (byte-identical to the passing round-14 version)
#define OFF_WD1 0        // 256x128 f16 = 65536
#define OFF_WD2 65536    // 64x256 f16  = 32768
#define OFF_DTS 98304    // 249 f32 -> 4096
#define OFF_ZP 102400    // 8 slices x 48B = 384
#define OFF_H1P 102784   // 8 slices x 80B = 640
#define OFF_H2P 103424   // 8 slices x 80B = 640
#define OFF_HDP 104064   // 8 slices x 80B = 640
#define OFF_ZP2 104704   // 8 slices x 48B = 384
#define OFF_HDP2 105088  // 8 slices x 80B = 640
#define SMEM_BYTES 105728

__global__ __launch_bounds__(1024, 1) void k_ode(
    const float* __restrict__ tarr, const float* __restrict__ z0in,
    const float* __restrict__ Wo1, const float* __restrict__ bo1p,
    const float* __restrict__ Wo2, const float* __restrict__ bo2p,
    const float* __restrict__ Wo3, const float* __restrict__ bo3p,
    const float* __restrict__ Wd1, const float* __restrict__ bd1p,
    const float* __restrict__ Wd2, const float* __restrict__ bd2p,
    float* __restrict__ out) {
  extern __shared__ char smem[];
  _Float16* wd1s = (_Float16*)(smem + OFF_WD1);
  _Float16* wd2s = (_Float16*)(smem + OFF_WD2);
  float* dts = (float*)(smem + OFF_DTS);
  _Float16* zp = (_Float16*)(smem + OFF_ZP);
  _Float16* h1p = (_Float16*)(smem + OFF_H1P);
  _Float16* h2p = (_Float16*)(smem + OFF_H2P);
  _Float16* hdp = (_Float16*)(smem + OFF_HDP);
  _Float16* zp2 = (_Float16*)(smem + OFF_ZP2);
  _Float16* hdp2 = (_Float16*)(smem + OFF_HDP2);

  const int n = blockIdx.x;
  const int t = threadIdx.x;
  const int q8 = t >> 3, e8 = t & 7;
  const int g16 = t >> 4, s16 = t & 15;

  h2 wL1[2][8];   // Wo1 rows {2q8,2q8+1} x cols 16e8..16e8+15
  h2 wL2[2][16];  // Wo2 rows {2q8,2q8+1} x cols 32e8..32e8+31
  h2 wL3[16];     // Wo3 row q8 x cols 32e8..32e8+31
  float bo1r[2], bo2r[2], bd1r[2];
#pragma unroll
  for (int i = 0; i < 2; ++i) {
    const float4* p1 = (const float4*)(Wo1 + (2 * q8 + i) * ZZ + 16 * e8);
#pragma unroll
    for (int j4 = 0; j4 < 4; ++j4) {
      float4 v = p1[j4];
      wL1[i][2 * j4] = pack2(v.x, v.y);
      wL1[i][2 * j4 + 1] = pack2(v.z, v.w);
    }
    const float4* p2 = (const float4*)(Wo2 + (2 * q8 + i) * HIDN + 32 * e8);
#pragma unroll
    for (int j4 = 0; j4 < 8; ++j4) {
      float4 v = p2[j4];
      wL2[i][2 * j4] = pack2(v.x, v.y);
      wL2[i][2 * j4 + 1] = pack2(v.z, v.w);
    }
    bo1r[i] = bo1p[2 * q8 + i];
    bo2r[i] = bo2p[2 * q8 + i];
    bd1r[i] = bd1p[2 * q8 + i];
  }
  {
    const float4* p3 = (const float4*)(Wo3 + q8 * HIDN + 32 * e8);
#pragma unroll
    for (int j4 = 0; j4 < 8; ++j4) {
      float4 v = p3[j4];
      wL3[2 * j4] = pack2(v.x, v.y);
      wL3[2 * j4 + 1] = pack2(v.z, v.w);
    }
  }
  const float bo3r = bo3p[q8];
  const float bd2r = bd2p[g16];

  // stage decoder weights (f16) + quad-step dt table to LDS
#pragma unroll 1
  for (int idx = t; idx < HIDN * ZZ; idx += 1024)
    wd1s[idx] = (_Float16)Wd1[idx];
#pragma unroll 1
  for (int idx = t; idx < DD * HIDN; idx += 1024)
    wd2s[idx] = (_Float16)Wd2[idx];
#pragma unroll 1
  for (int idx = t; idx < (SS - 4) / 4 + 1; idx += 1024)
    dts[idx] = tarr[4 * idx + 4] - tarr[4 * idx];  // H = 4*dt, j = 0..248
  const float dt2 = tarr[SS - 2] - tarr[SS - 4];   // 996 -> 998
  const float dtt = tarr[SS - 1] - tarr[SS - 2];   // 998 -> 999

  // z state: row q8 (1:1 group<->row), replicated across the 8 e8 lanes
  float zv = z0in[(size_t)n * ZZ + q8];
  if (t < 32) {
    const float4 zl = *(const float4*)(z0in + (size_t)n * ZZ + 4 * t);
    h4 pk;
    pk[0] = (_Float16)zl.x; pk[1] = (_Float16)zl.y;
    pk[2] = (_Float16)zl.z; pk[3] = (_Float16)zl.w;
    *(h4*)((char*)zp + (t >> 2) * 48 + (t & 3) * 8) = pk;
  }

  // hoisted LDS addresses
  const char* zrd = (const char*)zp + e8 * 48;
  const char* zrd2 = (const char*)zp2 + e8 * 48;
  const char* h1rd = (const char*)h1p + e8 * 80;
  const char* h2rd = (const char*)h2p + e8 * 80;
  const char* hdrd = (const char*)hdp + (s16 >> 1) * 80 + (s16 & 1) * 32;
  const char* hdrd2 = (const char*)hdp2 + (s16 >> 1) * 80 + (s16 & 1) * 32;
  char* h1wr = (char*)h1p + ((2 * q8) >> 5) * 80 + ((2 * q8) & 31) * 2;
  char* h2wr = (char*)h2p + ((2 * q8) >> 5) * 80 + ((2 * q8) & 31) * 2;
  char* hdwr = (char*)hdp + ((2 * q8) >> 5) * 80 + ((2 * q8) & 31) * 2;
  char* hdwr2 = (char*)hdp2 + ((2 * q8) >> 5) * 80 + ((2 * q8) & 31) * 2;
  _Float16* zwr = (_Float16*)((char*)zp + (q8 >> 4) * 48) + (q8 & 15);
  _Float16* zwr2 = (_Float16*)((char*)zp2 + (q8 >> 4) * 48) + (q8 & 15);
  const _Float16* wd1r = wd1s + (2 * q8) * ZZ + 16 * e8;
  const _Float16* wd2r = wd2s + g16 * HIDN + 16 * s16;

  // D1: decoder layer 1 from a z fragment, writing the given hd buffer
  auto D1w = [&](const h2* cz, char* hw) {
    h2 w0[8], w1[8];
    {
      const uint4* p0 = (const uint4*)wd1r;
      u4c(p0[0], w0); u4c(p0[1], w0 + 4);
      const uint4* p1 = (const uint4*)(wd1r + ZZ);
      u4c(p1[0], w1); u4c(p1[1], w1 + 4);
    }
    float a0 = 0.f, a1 = 0.f;
#pragma unroll
    for (int j = 0; j < 8; ++j) {
      a0 = fdot2(w0[j], cz[j], a0);
      a1 = fdot2(w1[j], cz[j], a1);
    }
    a0 = red8(a0);
    a1 = red8(a1);
    if (e8 == 0) {
      float v0 = a0 + bd1r[0], v1 = a1 + bd1r[1];
      v0 = v0 > 0.f ? v0 : 0.f;
      v1 = v1 > 0.f ? v1 : 0.f;
      *(h2*)hw = pack2(v0, v1);
    }
  };
  // D2: decoder layer 2 from the given hd buffer -> f32 out (proven path)
  auto D2r = [&](int sidx, const char* hr) {
    h2 w[8], hh[8];
    {
      const uint4* pw = (const uint4*)wd2r;
      u4c(pw[0], w); u4c(pw[1], w + 4);
      const uint4* ph = (const uint4*)hr;
      u4c(ph[0], hh); u4c(ph[1], hh + 4);
    }
    float a = 0.f;
#pragma unroll
    for (int j = 0; j < 8; ++j) a = fdot2(w[j], hh[j], a);
    a = red16(a);
    if (s16 == 0) out[((size_t)n * SS + sidx) * DD + g16] = a + bd2r;
  };
  auto load_z = [&](h2* cz, const char* base) {
    const uint4* zq = (const uint4*)base;
    uint4 u0 = zq[0], u1 = zq[1];
    u4c(u0, cz); u4c(u1, cz + 4);
  };

  // standalone decode (used for sidx=0 and sidx=SS-1)
  auto decode_standalone = [&](int sidx) {
    __syncthreads();
    h2 cz[8];
    load_z(cz, zrd);
    D1w(cz, hdwr);
    __syncthreads();
    D2r(sidx, hdrd);
  };

  // One RK2 double-stage with up to 2 folded decodes per sub-stage.
  // st0: k1 at z; writes zp<-zmid, zp2<-z+(H/4)k1 (if wAux).
  // st1: k2 at zmid; z += H*k2; writes zp<-z, zp2<-z_old+(3H/4)k2 (if wAux).
  auto two_stage = [&](float Hv, bool m0, int sm0, bool a0x, int sa0,
                       bool m1, int sm1, bool a1x, int sa1, bool wAux) {
#pragma unroll
    for (int st = 0; st < 2; ++st) {
      const bool dM = st ? m1 : m0;
      const bool dA = st ? a1x : a0x;
      const int sM = st ? sm1 : sm0;
      const int sA = st ? sa1 : sa0;
      __syncthreads();  // zp/zp2 (and prior-phase buffers) ready
      // ---- phase A: L1 (+ folded D1 main/aux) ----
      {
        h2 cz[8];
        load_z(cz, zrd);
        if (dM) D1w(cz, hdwr);
        if (dA) {
          h2 cz2[8];
          load_z(cz2, zrd2);
          D1w(cz2, hdwr2);
        }
        float a0 = 0.f, a1 = 0.f;
#pragma unroll
        for (int j = 0; j < 8; ++j) {
          a0 = fdot2(wL1[0][j], cz[j], a0);
          a1 = fdot2(wL1[1][j], cz[j], a1);
        }
        a0 = red8(a0);
        a1 = red8(a1);
        if (e8 == 0)
          *(h2*)h1wr = pack2(elu1(a0 + bo1r[0]), elu1(a1 + bo1r[1]));
      }
      __syncthreads();
      // ---- phase B: L2 (+ folded D2 main/aux) ----
      {
        if (dM) D2r(sM, hdrd);
        if (dA) D2r(sA, hdrd2);
        h2 ch[16];
        const uint4* hq = (const uint4*)h1rd;
        uint4 u0 = hq[0], u1 = hq[1], u2 = hq[2], u3 = hq[3];
        u4c(u0, ch); u4c(u1, ch + 4); u4c(u2, ch + 8); u4c(u3, ch + 12);
        float a0 = 0.f, a1 = 0.f;
#pragma unroll
        for (int j = 0; j < 16; ++j) {
          a0 = fdot2(wL2[0][j], ch[j], a0);
          a1 = fdot2(wL2[1][j], ch[j], a1);
        }
        a0 = red8(a0);
        a1 = red8(a1);
        if (e8 == 0)
          *(h2*)h2wr = pack2(elu1(a0 + bo2r[0]), elu1(a1 + bo2r[1]));
      }
      __syncthreads();
      // ---- phase C: L3 + RK2 update (row q8) ----
      {
        h2 ch[16];
        const uint4* hq = (const uint4*)h2rd;
        uint4 u0 = hq[0], u1 = hq[1], u2 = hq[2], u3 = hq[3];
        u4c(u0, ch); u4c(u1, ch + 4); u4c(u2, ch + 8); u4c(u3, ch + 12);
        float a = 0.f;
#pragma unroll
        for (int j = 0; j < 16; ++j) a = fdot2(wL3[j], ch[j], a);
        a = red8(a);
        const float f = a + bo3r;  // valid in all 8 lanes of the group
        float zc, za;
        if (st == 0) {
          zc = zv + 0.5f * Hv * f;   // zmid = z + (H/2)*k1
          za = zv + 0.25f * Hv * f;  // est pos +1
        } else {
          const float zo = zv;
          zv += Hv * f;  // z += H*k2
          zc = zv;
          za = zo + 0.75f * Hv * f;  // est pos +3 (consumed next stage)
        }
        if (e8 == 0) {
          *zwr = (_Float16)zc;
          if (wAux) *zwr2 = (_Float16)za;
        }
      }
    }
  };

  __syncthreads();  // dts, zp, wd1s/wd2s staged
  decode_standalone(0);

#pragma unroll 1
  for (int j = 0; j < 249; ++j) {
    // st0: main=pos 4j (j>0), aux=pos 4j-1 (j>0, from zp2 of prev stage)
    // st1: main=pos 4j+2 (zmid), aux=pos 4j+1 (zp2 = z+(H/4)k1)
    two_stage(dts[j], j > 0, 4 * j, j > 0, 4 * j - 1, true, 4 * j + 2, true,
              4 * j + 1, true);
  }
  // z = z_996; zp2 holds est of pos 995.
  // H=2dt step 996->998: st0 decodes 996(main)+995(aux); st1 decodes 997
  // from the true midpoint.
  two_stage(dt2, true, SS - 4, true, SS - 5, true, SS - 3, false, 0, false);
  // H=dt step 998->999: st0 decodes 998.
  two_stage(dtt, true, SS - 2, false, 0, false, 0, false, 0, false);
  decode_standalone(SS - 1);
}

extern "C" void kernel_launch(void* const* d_in, const int* in_sizes, int n_in,
                              void* d_out, int out_size, void* d_ws,
                              size_t ws_size, hipStream_t stream) {
  const float* X = (const float*)d_in[0];
  const float* tarr = (const float*)d_in[1];
  const float* eps = (const float*)d_in[2];
  const float* Wih = (const float*)d_in[3];
  const float* Whh = (const float*)d_in[4];
  const float* bih = (const float*)d_in[5];
  const float* bhh = (const float*)d_in[6];
  const float* Wcomp = (const float*)d_in[7];
  const float* bcomp = (const float*)d_in[8];
  const float* Wrc = (const float*)d_in[9];
  const float* brc = (const float*)d_in[10];
  const float* Wo1 = (const float*)d_in[11];
  const float* bo1 = (const float*)d_in[12];
  const float* Wo2 = (const float*)d_in[13];
  const float* bo2 = (const float*)d_in[14];
  const float* Wo3 = (const float*)d_in[15];
  const float* bo3 = (const float*)d_in[16];
  const float* Wd1 = (const float*)d_in[17];
  const float* bd1 = (const float*)d_in[18];
  const float* Wd2 = (const float*)d_in[19];
  const float* bd2 = (const float*)d_in[20];
  float* out = (float*)d_out;
  float* z0ws = (float*)d_ws;  // 256*128 f32 = 128 KiB

  k_rnn<<<dim3(NN), dim3(512), 0, stream>>>(X, Wih, Whh, bih, bhh, Wcomp,
                                            bcomp, eps, Wrc, brc, z0ws);
  k_ode<<<dim3(NN), dim3(1024), SMEM_BYTES, stream>>>(
      tarr, z0ws, Wo1, bo1, Wo2, bo2, Wo3, bo3, Wd1, bd1, Wd2, bd2, out);
}

// Round 17
// 1828.962 us; speedup vs baseline: 1.0766x; 1.0334x over previous
//
#include <hip/hip_runtime.h>

typedef _Float16 h2 __attribute__((ext_vector_type(2)));
typedef _Float16 h4 __attribute__((ext_vector_type(4)));

#define NN 256
#define SS 1000
#define DD 64
#define HH 256
#define ZZ 128
#define HIDN 256

__device__ __forceinline__ float fdot2(h2 a, h2 b, float c) {
  return __builtin_amdgcn_fdot2(a, b, c, false);
}
__device__ __forceinline__ float fast_tanh(float x) {
  float e = __expf(2.0f * x);
  return 1.0f - 2.0f / (e + 1.0f);
}
__device__ __forceinline__ float elu1(float x) {
  return x > 0.0f ? x : (__expf(x) - 1.0f);
}
__device__ __forceinline__ h2 pack2(float a, float b) {
  h2 r; r.x = (_Float16)a; r.y = (_Float16)b; return r;
}
__device__ __forceinline__ void u4c(uint4 u, h2* c) {
  c[0] = __builtin_bit_cast(h2, u.x);
  c[1] = __builtin_bit_cast(h2, u.y);
  c[2] = __builtin_bit_cast(h2, u.z);
  c[3] = __builtin_bit_cast(h2, u.w);
}
// DPP cross-lane adds (numerics proven identical to shfl_xor in r5/r6).
template <int CTRL>
__device__ __forceinline__ float dppadd(float a) {
  int x = __builtin_bit_cast(int, a);
  int y = __builtin_amdgcn_update_dpp(0, x, CTRL, 0xf, 0xf, true);
  return a + __builtin_bit_cast(float, y);
}
__device__ __forceinline__ float red4(float a) {
  a = dppadd<0xB1>(a); a = dppadd<0x4E>(a); return a;
}
__device__ __forceinline__ float red8(float a) {
  a = dppadd<0x141>(a); a = dppadd<0x4E>(a); a = dppadd<0xB1>(a); return a;
}
__device__ __forceinline__ float red16(float a) {
  a = dppadd<0x140>(a); a = dppadd<0x141>(a); a = dppadd<0x4E>(a);
  a = dppadd<0xB1>(a); return a;
}

// ---------------- Kernel 1: reverse RNN + encoder -> z0 ----------------
// (byte-identical to the passing round-16 version)
__global__ __launch_bounds__(512, 2) void k_rnn(
    const float* __restrict__ X, const float* __restrict__ Wih,
    const float* __restrict__ Whh, const float* __restrict__ bih,
    const float* __restrict__ bhh, const float* __restrict__ Wcomp,
    const float* __restrict__ bcomp, const float* __restrict__ eps,
    const float* __restrict__ Wrc, const float* __restrict__ brc,
    float* __restrict__ z0out) {
  const int n = blockIdx.x;
  const int t = threadIdx.x;
  const int g = t >> 2, c = t & 3;
  __shared__ __align__(16) _Float16 hb[2][HH];       // contiguous h state
  __shared__ __align__(16) _Float16 xc[2][16][DD];   // 2 x 16-step x chunks
  __shared__ float comp_s[HH];
  __shared__ float zenc_s[ZZ];

  h2 wih2[2][8];   // rows {2g,2g+1} x cols 16c..16c+15
  h2 whh2[2][32];  // rows {2g,2g+1} x cols 64c..64c+63
  float bi2[2];
#pragma unroll
  for (int i = 0; i < 2; ++i) {
    const float4* wp = (const float4*)(Wih + (2 * g + i) * DD + 16 * c);
#pragma unroll
    for (int j4 = 0; j4 < 4; ++j4) {
      float4 v = wp[j4];
      wih2[i][2 * j4] = pack2(v.x, v.y);
      wih2[i][2 * j4 + 1] = pack2(v.z, v.w);
    }
    const float4* hp = (const float4*)(Whh + (2 * g + i) * HH + 64 * c);
#pragma unroll
    for (int j4 = 0; j4 < 16; ++j4) {
      float4 v = hp[j4];
      whh2[i][2 * j4] = pack2(v.x, v.y);
      whh2[i][2 * j4 + 1] = pack2(v.z, v.w);
    }
    bi2[i] = bih[2 * g + i] + bhh[2 * g + i];
  }
  // stage chunk cn (steps 16cn..16cn+15): 512 thr x float2 = 16 rows x 64
  auto stage = [&](int cn) {
    const int row = t >> 5;          // 0..15
    const int sp = 16 * cn + row;    // step index
    if (sp < SS) {
      const float2 v =
          ((const float2*)(X + ((size_t)n * SS + (SS - 1 - sp)) * DD))[t & 31];
      *(h2*)(&xc[cn & 1][row][(t & 31) * 2]) = pack2(v.x, v.y);
    }
  };
  if (t < HH) hb[0][t] = (_Float16)0.0f;
  stage(0);
  int cur = 0;
#pragma unroll 1
  for (int s = 0; s < SS; ++s) {
    __syncthreads();  // xc chunk, hb[cur] ready
    if ((s & 15) == 0) {
      const int cn = (s >> 4) + 1;
      if (16 * cn < SS) stage(cn);  // prefetch next chunk (other buffer)
    }
    h2 cx[8];   // x quarter: 16 f16
    h2 ch[32];  // h quarter: 64 f16
    {
      const uint4* xq = (const uint4*)(&xc[(s >> 4) & 1][s & 15][16 * c]);
      u4c(xq[0], cx);
      u4c(xq[1], cx + 4);
      const uint4* hq = (const uint4*)(hb[cur] + 64 * c);
#pragma unroll
      for (int j4 = 0; j4 < 8; ++j4) u4c(hq[j4], ch + 4 * j4);
    }
    float a0 = 0.f, a1 = 0.f;
#pragma unroll
    for (int j = 0; j < 8; ++j) {
      a0 = fdot2(wih2[0][j], cx[j], a0);
      a1 = fdot2(wih2[1][j], cx[j], a1);
    }
#pragma unroll
    for (int j = 0; j < 32; ++j) {
      a0 = fdot2(whh2[0][j], ch[j], a0);
      a1 = fdot2(whh2[1][j], ch[j], a1);
    }
    a0 = red4(a0);
    a1 = red4(a1);
    if (c == 0)
      ((h2*)hb[cur ^ 1])[g] =
          pack2(fast_tanh(a0 + bi2[0]), fast_tanh(a1 + bi2[1]));
    cur ^= 1;
  }
  __syncthreads();
  // ---- encoder epilogue (one-time) ----
  const int r2 = t >> 1, c2 = t & 1;
  {
    float a = c2 ? 0.0f : bcomp[r2];
    const float4* wc = (const float4*)(Wcomp + r2 * HH + c2 * 128);
#pragma unroll 8
    for (int j = 0; j < 32; ++j) {
      float4 w = wc[j];
      a += w.x * (float)hb[cur][c2 * 128 + 4 * j + 0] +
           w.y * (float)hb[cur][c2 * 128 + 4 * j + 1] +
           w.z * (float)hb[cur][c2 * 128 + 4 * j + 2] +
           w.w * (float)hb[cur][c2 * 128 + 4 * j + 3];
    }
    a += __shfl_xor(a, 1);
    if (!c2) comp_s[r2] = a;
  }
  __syncthreads();
  if (t < ZZ) {
    float mu = comp_s[t];
    float sd = comp_s[t + ZZ];
    zenc_s[t] = eps[(size_t)n * ZZ + t] * sd + mu;
  }
  __syncthreads();
  {
    const int r4 = t >> 2, c4 = t & 3;
    float a = c4 ? 0.0f : brc[r4];
    const float4* wr = (const float4*)(Wrc + r4 * ZZ + c4 * 32);
    const float* zl = zenc_s + c4 * 32;
#pragma unroll
    for (int j = 0; j < 8; ++j) {
      float4 w = wr[j];
      a += w.x * zl[4 * j + 0] + w.y * zl[4 * j + 1] + w.z * zl[4 * j + 2] +
           w.w * zl[4 * j + 3];
    }
    a += __shfl_xor(a, 1);
    a += __shfl_xor(a, 2);
    if (!c4) z0out[(size_t)n * ZZ + r4] = a;
  }
}

// ------- Kernel 2: ODE, RK2 H=4dt, integrate-then-BURST-decode -----------
// 252 stash entries: j=0..248 quad steps (H=4dt), 249 (H=2dt), 250 (H=dt),
// 251 final-z. Per 16-entry chunk: serial sub-stages stash (z,k1,k2,H),
// then a parallel burst decodes that chunk's <=64 positions:
//   p<996: e=p>>2, ic=p&3; 996:(249,0) 997:(249,2) 998:(250,0) 999:(251,0)
//   ic: 0 -> z; 1 -> z+(H/4)k1; 2 -> z+(H/2)k1; 3 -> z+(3H/4)k2
// (identical fp formulas to r14 -> bit-identical quantization).
// Decoder weights live in REGISTERS (24 VGPR); no LDS weight buffers.
#define OFF_STZ 0        // 16 x 128 f32 = 8192
#define OFF_STK1 8192    // 8192
#define OFF_STK2 16384   // 8192
#define OFF_STH 24576    // 16 f32 -> 64
#define OFF_DTS 24640    // 249 f32 -> pad 1024
#define OFF_ZP 25664     // 8 x 48B = 384
#define OFF_H1P 26048    // 8 x 80B = 640
#define OFF_H2P 26688    // 8 x 80B = 640
#define OFF_ZEST 27328   // 64 x 256B = 16384
#define OFF_HDB 43712    // 64 x 640B = 40960
#define SMEM_BYTES 84672

__global__ __launch_bounds__(1024, 1) void k_ode(
    const float* __restrict__ tarr, const float* __restrict__ z0in,
    const float* __restrict__ Wo1, const float* __restrict__ bo1p,
    const float* __restrict__ Wo2, const float* __restrict__ bo2p,
    const float* __restrict__ Wo3, const float* __restrict__ bo3p,
    const float* __restrict__ Wd1, const float* __restrict__ bd1p,
    const float* __restrict__ Wd2, const float* __restrict__ bd2p,
    float* __restrict__ out) {
  extern __shared__ char smem[];
  float* stz = (float*)(smem + OFF_STZ);    // [16][128]
  float* stk1 = (float*)(smem + OFF_STK1);  // [16][128]
  float* stk2 = (float*)(smem + OFF_STK2);  // [16][128]
  float* stH = (float*)(smem + OFF_STH);    // [16]
  float* dts = (float*)(smem + OFF_DTS);
  _Float16* zp = (_Float16*)(smem + OFF_ZP);
  _Float16* h1p = (_Float16*)(smem + OFF_H1P);
  _Float16* h2p = (_Float16*)(smem + OFF_H2P);
  _Float16* zest = (_Float16*)(smem + OFF_ZEST);  // [64][128]
  char* hdb = smem + OFF_HDB;                     // [64][640B]

  const int n = blockIdx.x;
  const int t = threadIdx.x;
  const int q8 = t >> 3, e8 = t & 7;
  const int g16 = t >> 4, s16 = t & 15;

  h2 wL1[2][8];   // Wo1 rows {2q8,2q8+1} x cols 16e8..16e8+15
  h2 wL2[2][16];  // Wo2 rows {2q8,2q8+1} x cols 32e8..32e8+31
  h2 wL3[16];     // Wo3 row q8 x cols 32e8..32e8+31
  h2 wD1[2][8];   // Wd1 rows {2q8,2q8+1} x cols 16e8..16e8+15 (registers)
  h2 wD2[8];      // Wd2 row g16 x cols 16s16..16s16+15 (registers)
  float bo1r[2], bo2r[2], bd1r[2];
#pragma unroll
  for (int i = 0; i < 2; ++i) {
    const float4* p1 = (const float4*)(Wo1 + (2 * q8 + i) * ZZ + 16 * e8);
#pragma unroll
    for (int j4 = 0; j4 < 4; ++j4) {
      float4 v = p1[j4];
      wL1[i][2 * j4] = pack2(v.x, v.y);
      wL1[i][2 * j4 + 1] = pack2(v.z, v.w);
    }
    const float4* p2 = (const float4*)(Wo2 + (2 * q8 + i) * HIDN + 32 * e8);
#pragma unroll
    for (int j4 = 0; j4 < 8; ++j4) {
      float4 v = p2[j4];
      wL2[i][2 * j4] = pack2(v.x, v.y);
      wL2[i][2 * j4 + 1] = pack2(v.z, v.w);
    }
    const float4* pd = (const float4*)(Wd1 + (2 * q8 + i) * ZZ + 16 * e8);
#pragma unroll
    for (int j4 = 0; j4 < 4; ++j4) {
      float4 v = pd[j4];
      wD1[i][2 * j4] = pack2(v.x, v.y);
      wD1[i][2 * j4 + 1] = pack2(v.z, v.w);
    }
    bo1r[i] = bo1p[2 * q8 + i];
    bo2r[i] = bo2p[2 * q8 + i];
    bd1r[i] = bd1p[2 * q8 + i];
  }
  {
    const float4* p3 = (const float4*)(Wo3 + q8 * HIDN + 32 * e8);
#pragma unroll
    for (int j4 = 0; j4 < 8; ++j4) {
      float4 v = p3[j4];
      wL3[2 * j4] = pack2(v.x, v.y);
      wL3[2 * j4 + 1] = pack2(v.z, v.w);
    }
    const float4* pd2 = (const float4*)(Wd2 + g16 * HIDN + 16 * s16);
#pragma unroll
    for (int j4 = 0; j4 < 4; ++j4) {
      float4 v = pd2[j4];
      wD2[2 * j4] = pack2(v.x, v.y);
      wD2[2 * j4 + 1] = pack2(v.z, v.w);
    }
  }
  const float bo3r = bo3p[q8];
  const float bd2r = bd2p[g16];

  // dt table for the 249 quad steps
#pragma unroll 1
  for (int idx = t; idx < 249; idx += 1024)
    dts[idx] = tarr[4 * idx + 4] - tarr[4 * idx];  // H = 4*dt
  const float dt2 = tarr[SS - 2] - tarr[SS - 4];   // 996 -> 998
  const float dtt = tarr[SS - 1] - tarr[SS - 2];   // 998 -> 999

  // z state: row q8, replicated across the 8 e8 lanes
  float zv = z0in[(size_t)n * ZZ + q8];
  if (t < 32) {
    const float4 zl = *(const float4*)(z0in + (size_t)n * ZZ + 4 * t);
    h4 pk;
    pk[0] = (_Float16)zl.x; pk[1] = (_Float16)zl.y;
    pk[2] = (_Float16)zl.z; pk[3] = (_Float16)zl.w;
    *(h4*)((char*)zp + (t >> 2) * 48 + (t & 3) * 8) = pk;
  }

  // hoisted LDS addresses (r14-proven phase-buffer patterns)
  const char* zrd = (const char*)zp + e8 * 48;
  const char* h1rd = (const char*)h1p + e8 * 80;
  const char* h2rd = (const char*)h2p + e8 * 80;
  char* h1wr = (char*)h1p + ((2 * q8) >> 5) * 80 + ((2 * q8) & 31) * 2;
  char* h2wr = (char*)h2p + ((2 * q8) >> 5) * 80 + ((2 * q8) & 31) * 2;
  _Float16* zwr = (_Float16*)((char*)zp + (q8 >> 4) * 48) + (q8 & 15);
  const int hdwr_off = ((2 * q8) >> 5) * 80 + ((2 * q8) & 31) * 2;
  const int hdrd_off = (s16 >> 1) * 80 + (s16 & 1) * 32;

  // One RK2 double-stage, no folded decode; stashes z,k1,k2,H at entry el.
  auto two_stage_ns = [&](float Hv, int el) {
#pragma unroll
    for (int st = 0; st < 2; ++st) {
      __syncthreads();  // zp (and prior-phase buffers) ready
      // ---- phase A: L1 ----
      {
        h2 cz[8];
        const uint4* zq = (const uint4*)zrd;
        uint4 u0 = zq[0], u1 = zq[1];
        u4c(u0, cz); u4c(u1, cz + 4);
        float a0 = 0.f, a1 = 0.f;
#pragma unroll
        for (int j = 0; j < 8; ++j) {
          a0 = fdot2(wL1[0][j], cz[j], a0);
          a1 = fdot2(wL1[1][j], cz[j], a1);
        }
        a0 = red8(a0);
        a1 = red8(a1);
        if (e8 == 0)
          *(h2*)h1wr = pack2(elu1(a0 + bo1r[0]), elu1(a1 + bo1r[1]));
      }
      __syncthreads();
      // ---- phase B: L2 ----
      {
        h2 ch[16];
        const uint4* hq = (const uint4*)h1rd;
        uint4 u0 = hq[0], u1 = hq[1], u2 = hq[2], u3 = hq[3];
        u4c(u0, ch); u4c(u1, ch + 4); u4c(u2, ch + 8); u4c(u3, ch + 12);
        float a0 = 0.f, a1 = 0.f;
#pragma unroll
        for (int j = 0; j < 16; ++j) {
          a0 = fdot2(wL2[0][j], ch[j], a0);
          a1 = fdot2(wL2[1][j], ch[j], a1);
        }
        a0 = red8(a0);
        a1 = red8(a1);
        if (e8 == 0)
          *(h2*)h2wr = pack2(elu1(a0 + bo2r[0]), elu1(a1 + bo2r[1]));
      }
      __syncthreads();
      // ---- phase C: L3 + RK2 update + stash ----
      {
        h2 ch[16];
        const uint4* hq = (const uint4*)h2rd;
        uint4 u0 = hq[0], u1 = hq[1], u2 = hq[2], u3 = hq[3];
        u4c(u0, ch); u4c(u1, ch + 4); u4c(u2, ch + 8); u4c(u3, ch + 12);
        float a = 0.f;
#pragma unroll
        for (int j = 0; j < 16; ++j) a = fdot2(wL3[j], ch[j], a);
        a = red8(a);
        const float f = a + bo3r;  // valid in all 8 lanes of the group
        float zc;
        if (st == 0) {
          if (e8 == 0) {
            stz[el * 128 + q8] = zv;   // z at entry start
            stk1[el * 128 + q8] = f;   // k1
          }
          if (t == 0) stH[el] = Hv;
          zc = zv + 0.5f * Hv * f;  // zmid
        } else {
          if (e8 == 0) stk2[el * 128 + q8] = f;  // k2
          zv += Hv * f;
          zc = zv;
        }
        if (e8 == 0) *zwr = (_Float16)zc;
      }
    }
  };

  // ---------------- main loop: 16 chunks of (serial + burst) -------------
#pragma unroll 1
  for (int chunk = 0; chunk < 16; ++chunk) {
    const int e0 = 16 * chunk;
    const int e_end = (e0 + 16 < 252) ? e0 + 16 : 252;
#pragma unroll 1
    for (int e = e0; e < e_end; ++e) {
      const int el = e & 15;
      if (e < 249) {
        two_stage_ns(dts[e], el);
      } else if (e == 249) {
        two_stage_ns(dt2, el);
      } else if (e == 250) {
        two_stage_ns(dtt, el);
      } else {  // 251: stash final z only
        if (e8 == 0) stz[el * 128 + q8] = zv;
      }
    }
    __syncthreads();  // stash complete
    const int p0 = 64 * chunk;
    const int P = (1000 - p0 < 64) ? (1000 - p0) : 64;
    // ---- phase ZEST: z-estimates for all P positions (f32 -> f16) ----
#pragma unroll 1
    for (int idx = t; idx < P * 64; idx += 1024) {
      const int lp = idx >> 6, pr = idx & 63;
      const int p = p0 + lp;
      int ee, ic;
      if (p < 996) {
        ee = (p >> 2) & 15;
        ic = p & 3;
      } else if (p == 996) {
        ee = 249 & 15; ic = 0;
      } else if (p == 997) {
        ee = 249 & 15; ic = 2;
      } else if (p == 998) {
        ee = 250 & 15; ic = 0;
      } else {
        ee = 251 & 15; ic = 0;
      }
      float z0 = stz[ee * 128 + 2 * pr];
      float z1 = stz[ee * 128 + 2 * pr + 1];
      if (ic) {
        const float cc =
            stH[ee] * (ic == 1 ? 0.25f : (ic == 2 ? 0.5f : 0.75f));
        const float* kk = (ic == 3) ? stk2 : stk1;
        z0 += cc * kk[ee * 128 + 2 * pr];
        z1 += cc * kk[ee * 128 + 2 * pr + 1];
      }
      *(h2*)(zest + lp * 128 + 2 * pr) = pack2(z0, z1);
    }
    __syncthreads();
    // ---- phase D1-burst: all positions, back-to-back ----
#pragma unroll 1
    for (int lp = 0; lp < P; ++lp) {
      h2 cz[8];
      const uint4* zq = (const uint4*)((char*)zest + lp * 256 + e8 * 32);
      uint4 u0 = zq[0], u1 = zq[1];
      u4c(u0, cz); u4c(u1, cz + 4);
      float a0 = 0.f, a1 = 0.f;
#pragma unroll
      for (int j = 0; j < 8; ++j) {
        a0 = fdot2(wD1[0][j], cz[j], a0);
        a1 = fdot2(wD1[1][j], cz[j], a1);
      }
      a0 = red8(a0);
      a1 = red8(a1);
      if (e8 == 0) {
        float v0 = a0 + bd1r[0], v1 = a1 + bd1r[1];
        v0 = v0 > 0.f ? v0 : 0.f;
        v1 = v1 > 0.f ? v1 : 0.f;
        *(h2*)(hdb + lp * 640 + hdwr_off) = pack2(v0, v1);
      }
    }
    __syncthreads();
    // ---- phase D2-burst: all positions -> f32 out (proven path) ----
#pragma unroll 1
    for (int lp = 0; lp < P; ++lp) {
      h2 hh[8];
      const uint4* ph = (const uint4*)(hdb + lp * 640 + hdrd_off);
      uint4 u0 = ph[0], u1 = ph[1];
      u4c(u0, hh); u4c(u1, hh + 4);
      float a = 0.f;
#pragma unroll
      for (int j = 0; j < 8; ++j) a = fdot2(wD2[j], hh[j], a);
      a = red16(a);
      if (s16 == 0)
        out[((size_t)n * SS + (p0 + lp)) * DD + g16] = a + bd2r;
    }
    __syncthreads();  // hdb/zest/stash reusable by next chunk
  }
}

extern "C" void kernel_launch(void* const* d_in, const int* in_sizes, int n_in,
                              void* d_out, int out_size, void* d_ws,
                              size_t ws_size, hipStream_t stream) {
  const float* X = (const float*)d_in[0];
  const float* tarr = (const float*)d_in[1];
  const float* eps = (const float*)d_in[2];
  const float* Wih = (const float*)d_in[3];
  const float* Whh = (const float*)d_in[4];
  const float* bih = (const float*)d_in[5];
  const float* bhh = (const float*)d_in[6];
  const float* Wcomp = (const float*)d_in[7];
  const float* bcomp = (const float*)d_in[8];
  const float* Wrc = (const float*)d_in[9];
  const float* brc = (const float*)d_in[10];
  const float* Wo1 = (const float*)d_in[11];
  const float* bo1 = (const float*)d_in[12];
  const float* Wo2 = (const float*)d_in[13];
  const float* bo2 = (const float*)d_in[14];
  const float* Wo3 = (const float*)d_in[15];
  const float* bo3 = (const float*)d_in[16];
  const float* Wd1 = (const float*)d_in[17];
  const float* bd1 = (const float*)d_in[18];
  const float* Wd2 = (const float*)d_in[19];
  const float* bd2 = (const float*)d_in[20];
  float* out = (float*)d_out;
  float* z0ws = (float*)d_ws;  // 256*128 f32 = 128 KiB

  k_rnn<<<dim3(NN), dim3(512), 0, stream>>>(X, Wih, Whh, bih, bhh, Wcomp,
                                            bcomp, eps, Wrc, brc, z0ws);
  k_ode<<<dim3(NN), dim3(1024), SMEM_BYTES, stream>>>(
      tarr, z0ws, Wo1, bo1, Wo2, bo2, Wo3, bo3, Wd1, bd1, Wd2, bd2, out);
}

// Round 18
// 1547.841 us; speedup vs baseline: 1.2721x; 1.1816x over previous
//
#include <hip/hip_runtime.h>

typedef _Float16 h2 __attribute__((ext_vector_type(2)));
typedef _Float16 h4 __attribute__((ext_vector_type(4)));

#define NN 256
#define SS 1000
#define DD 64
#define HH 256
#define ZZ 128
#define HIDN 256

__device__ __forceinline__ float fdot2(h2 a, h2 b, float c) {
  return __builtin_amdgcn_fdot2(a, b, c, false);
}
__device__ __forceinline__ float fast_tanh(float x) {
  float e = __expf(2.0f * x);
  return 1.0f - 2.0f / (e + 1.0f);
}
__device__ __forceinline__ float elu1(float x) {
  return x > 0.0f ? x : (__expf(x) - 1.0f);
}
__device__ __forceinline__ h2 pack2(float a, float b) {
  h2 r; r.x = (_Float16)a; r.y = (_Float16)b; return r;
}
__device__ __forceinline__ void u4c(uint4 u, h2* c) {
  c[0] = __builtin_bit_cast(h2, u.x);
  c[1] = __builtin_bit_cast(h2, u.y);
  c[2] = __builtin_bit_cast(h2, u.z);
  c[3] = __builtin_bit_cast(h2, u.w);
}
// DPP cross-lane adds (numerics proven identical to shfl_xor in r5/r6).
template <int CTRL>
__device__ __forceinline__ float dppadd(float a) {
  int x = __builtin_bit_cast(int, a);
  int y = __builtin_amdgcn_update_dpp(0, x, CTRL, 0xf, 0xf, true);
  return a + __builtin_bit_cast(float, y);
}
__device__ __forceinline__ float red4(float a) {
  a = dppadd<0xB1>(a); a = dppadd<0x4E>(a); return a;
}
__device__ __forceinline__ float red8(float a) {
  a = dppadd<0x141>(a); a = dppadd<0x4E>(a); a = dppadd<0xB1>(a); return a;
}
__device__ __forceinline__ float red16(float a) {
  a = dppadd<0x140>(a); a = dppadd<0x141>(a); a = dppadd<0x4E>(a);
  a = dppadd<0xB1>(a); return a;
}

// ---------------- Kernel 1: reverse RNN + encoder -> z0 ----------------
// (byte-identical to the passing round-17 version)
__global__ __launch_bounds__(512, 2) void k_rnn(
    const float* __restrict__ X, const float* __restrict__ Wih,
    const float* __restrict__ Whh, const float* __restrict__ bih,
    const float* __restrict__ bhh, const float* __restrict__ Wcomp,
    const float* __restrict__ bcomp, const float* __restrict__ eps,
    const float* __restrict__ Wrc, const float* __restrict__ brc,
    float* __restrict__ z0out) {
  const int n = blockIdx.x;
  const int t = threadIdx.x;
  const int g = t >> 2, c = t & 3;
  __shared__ __align__(16) _Float16 hb[2][HH];       // contiguous h state
  __shared__ __align__(16) _Float16 xc[2][16][DD];   // 2 x 16-step x chunks
  __shared__ float comp_s[HH];
  __shared__ float zenc_s[ZZ];

  h2 wih2[2][8];   // rows {2g,2g+1} x cols 16c..16c+15
  h2 whh2[2][32];  // rows {2g,2g+1} x cols 64c..64c+63
  float bi2[2];
#pragma unroll
  for (int i = 0; i < 2; ++i) {
    const float4* wp = (const float4*)(Wih + (2 * g + i) * DD + 16 * c);
#pragma unroll
    for (int j4 = 0; j4 < 4; ++j4) {
      float4 v = wp[j4];
      wih2[i][2 * j4] = pack2(v.x, v.y);
      wih2[i][2 * j4 + 1] = pack2(v.z, v.w);
    }
    const float4* hp = (const float4*)(Whh + (2 * g + i) * HH + 64 * c);
#pragma unroll
    for (int j4 = 0; j4 < 16; ++j4) {
      float4 v = hp[j4];
      whh2[i][2 * j4] = pack2(v.x, v.y);
      whh2[i][2 * j4 + 1] = pack2(v.z, v.w);
    }
    bi2[i] = bih[2 * g + i] + bhh[2 * g + i];
  }
  // stage chunk cn (steps 16cn..16cn+15): 512 thr x float2 = 16 rows x 64
  auto stage = [&](int cn) {
    const int row = t >> 5;          // 0..15
    const int sp = 16 * cn + row;    // step index
    if (sp < SS) {
      const float2 v =
          ((const float2*)(X + ((size_t)n * SS + (SS - 1 - sp)) * DD))[t & 31];
      *(h2*)(&xc[cn & 1][row][(t & 31) * 2]) = pack2(v.x, v.y);
    }
  };
  if (t < HH) hb[0][t] = (_Float16)0.0f;
  stage(0);
  int cur = 0;
#pragma unroll 1
  for (int s = 0; s < SS; ++s) {
    __syncthreads();  // xc chunk, hb[cur] ready
    if ((s & 15) == 0) {
      const int cn = (s >> 4) + 1;
      if (16 * cn < SS) stage(cn);  // prefetch next chunk (other buffer)
    }
    h2 cx[8];   // x quarter: 16 f16
    h2 ch[32];  // h quarter: 64 f16
    {
      const uint4* xq = (const uint4*)(&xc[(s >> 4) & 1][s & 15][16 * c]);
      u4c(xq[0], cx);
      u4c(xq[1], cx + 4);
      const uint4* hq = (const uint4*)(hb[cur] + 64 * c);
#pragma unroll
      for (int j4 = 0; j4 < 8; ++j4) u4c(hq[j4], ch + 4 * j4);
    }
    float a0 = 0.f, a1 = 0.f;
#pragma unroll
    for (int j = 0; j < 8; ++j) {
      a0 = fdot2(wih2[0][j], cx[j], a0);
      a1 = fdot2(wih2[1][j], cx[j], a1);
    }
#pragma unroll
    for (int j = 0; j < 32; ++j) {
      a0 = fdot2(whh2[0][j], ch[j], a0);
      a1 = fdot2(whh2[1][j], ch[j], a1);
    }
    a0 = red4(a0);
    a1 = red4(a1);
    if (c == 0)
      ((h2*)hb[cur ^ 1])[g] =
          pack2(fast_tanh(a0 + bi2[0]), fast_tanh(a1 + bi2[1]));
    cur ^= 1;
  }
  __syncthreads();
  // ---- encoder epilogue (one-time) ----
  const int r2 = t >> 1, c2 = t & 1;
  {
    float a = c2 ? 0.0f : bcomp[r2];
    const float4* wc = (const float4*)(Wcomp + r2 * HH + c2 * 128);
#pragma unroll 8
    for (int j = 0; j < 32; ++j) {
      float4 w = wc[j];
      a += w.x * (float)hb[cur][c2 * 128 + 4 * j + 0] +
           w.y * (float)hb[cur][c2 * 128 + 4 * j + 1] +
           w.z * (float)hb[cur][c2 * 128 + 4 * j + 2] +
           w.w * (float)hb[cur][c2 * 128 + 4 * j + 3];
    }
    a += __shfl_xor(a, 1);
    if (!c2) comp_s[r2] = a;
  }
  __syncthreads();
  if (t < ZZ) {
    float mu = comp_s[t];
    float sd = comp_s[t + ZZ];
    zenc_s[t] = eps[(size_t)n * ZZ + t] * sd + mu;
  }
  __syncthreads();
  {
    const int r4 = t >> 2, c4 = t & 3;
    float a = c4 ? 0.0f : brc[r4];
    const float4* wr = (const float4*)(Wrc + r4 * ZZ + c4 * 32);
    const float* zl = zenc_s + c4 * 32;
#pragma unroll
    for (int j = 0; j < 8; ++j) {
      float4 w = wr[j];
      a += w.x * zl[4 * j + 0] + w.y * zl[4 * j + 1] + w.z * zl[4 * j + 2] +
           w.w * zl[4 * j + 3];
    }
    a += __shfl_xor(a, 1);
    a += __shfl_xor(a, 2);
    if (!c4) z0out[(size_t)n * ZZ + r4] = a;
  }
}

// ------- Kernel 2: ODE, RK2 H=8dt + quadratic dense output ---------------
// 128 stash entries: e=0..123 H=8dt steps, 124 (H=4dt), 125 (H=2dt),
// 126 (H=dt), 127 final-z. Per 8-entry chunk: serial sub-stages stash
// (z,k1,k2,H), then a burst decodes the chunk's <=64 positions using the
// RK2 dense-output quadratic  q(th) = z + H*(th*k1 + th^2*(k2-k1))
// (exact at th=0 and th=1=RK2 endpoint, slope-matching at 0 and mid;
//  decode-only error O(H^3)).
//   p<992: e=p>>3, th=(p&7)/8; 992-995: e=124, th=(p-992)/4;
//   996-997: e=125, th=(p-996)/2; 998: e=126, th=0; 999: e=127, th=0.
#define OFF_STZ 0        // 8 x 128 f32 = 4096
#define OFF_STK1 4096    // 4096
#define OFF_STK2 8192    // 4096
#define OFF_STH 12288    // 8 f32 -> 64
#define OFF_DTS 12352    // 124 f32 -> 512
#define OFF_ZP 12864     // 8 x 48B = 384
#define OFF_H1P 13248    // 8 x 80B = 640
#define OFF_H2P 13888    // 8 x 80B = 640
#define OFF_ZEST 14528   // 64 x 256B = 16384
#define OFF_HDB 30912    // 64 x 640B = 40960
#define SMEM_BYTES 71872

__global__ __launch_bounds__(1024, 1) void k_ode(
    const float* __restrict__ tarr, const float* __restrict__ z0in,
    const float* __restrict__ Wo1, const float* __restrict__ bo1p,
    const float* __restrict__ Wo2, const float* __restrict__ bo2p,
    const float* __restrict__ Wo3, const float* __restrict__ bo3p,
    const float* __restrict__ Wd1, const float* __restrict__ bd1p,
    const float* __restrict__ Wd2, const float* __restrict__ bd2p,
    float* __restrict__ out) {
  extern __shared__ char smem[];
  float* stz = (float*)(smem + OFF_STZ);    // [8][128]
  float* stk1 = (float*)(smem + OFF_STK1);  // [8][128]
  float* stk2 = (float*)(smem + OFF_STK2);  // [8][128]
  float* stH = (float*)(smem + OFF_STH);    // [8]
  float* dts = (float*)(smem + OFF_DTS);
  _Float16* zp = (_Float16*)(smem + OFF_ZP);
  _Float16* h1p = (_Float16*)(smem + OFF_H1P);
  _Float16* h2p = (_Float16*)(smem + OFF_H2P);
  _Float16* zest = (_Float16*)(smem + OFF_ZEST);  // [64][128]
  char* hdb = smem + OFF_HDB;                     // [64][640B]

  const int n = blockIdx.x;
  const int t = threadIdx.x;
  const int q8 = t >> 3, e8 = t & 7;
  const int g16 = t >> 4, s16 = t & 15;

  h2 wL1[2][8];   // Wo1 rows {2q8,2q8+1} x cols 16e8..16e8+15
  h2 wL2[2][16];  // Wo2 rows {2q8,2q8+1} x cols 32e8..32e8+31
  h2 wL3[16];     // Wo3 row q8 x cols 32e8..32e8+31
  h2 wD1[2][8];   // Wd1 rows {2q8,2q8+1} x cols 16e8..16e8+15 (registers)
  h2 wD2[8];      // Wd2 row g16 x cols 16s16..16s16+15 (registers)
  float bo1r[2], bo2r[2], bd1r[2];
#pragma unroll
  for (int i = 0; i < 2; ++i) {
    const float4* p1 = (const float4*)(Wo1 + (2 * q8 + i) * ZZ + 16 * e8);
#pragma unroll
    for (int j4 = 0; j4 < 4; ++j4) {
      float4 v = p1[j4];
      wL1[i][2 * j4] = pack2(v.x, v.y);
      wL1[i][2 * j4 + 1] = pack2(v.z, v.w);
    }
    const float4* p2 = (const float4*)(Wo2 + (2 * q8 + i) * HIDN + 32 * e8);
#pragma unroll
    for (int j4 = 0; j4 < 8; ++j4) {
      float4 v = p2[j4];
      wL2[i][2 * j4] = pack2(v.x, v.y);
      wL2[i][2 * j4 + 1] = pack2(v.z, v.w);
    }
    const float4* pd = (const float4*)(Wd1 + (2 * q8 + i) * ZZ + 16 * e8);
#pragma unroll
    for (int j4 = 0; j4 < 4; ++j4) {
      float4 v = pd[j4];
      wD1[i][2 * j4] = pack2(v.x, v.y);
      wD1[i][2 * j4 + 1] = pack2(v.z, v.w);
    }
    bo1r[i] = bo1p[2 * q8 + i];
    bo2r[i] = bo2p[2 * q8 + i];
    bd1r[i] = bd1p[2 * q8 + i];
  }
  {
    const float4* p3 = (const float4*)(Wo3 + q8 * HIDN + 32 * e8);
#pragma unroll
    for (int j4 = 0; j4 < 8; ++j4) {
      float4 v = p3[j4];
      wL3[2 * j4] = pack2(v.x, v.y);
      wL3[2 * j4 + 1] = pack2(v.z, v.w);
    }
    const float4* pd2 = (const float4*)(Wd2 + g16 * HIDN + 16 * s16);
#pragma unroll
    for (int j4 = 0; j4 < 4; ++j4) {
      float4 v = pd2[j4];
      wD2[2 * j4] = pack2(v.x, v.y);
      wD2[2 * j4 + 1] = pack2(v.z, v.w);
    }
  }
  const float bo3r = bo3p[q8];
  const float bd2r = bd2p[g16];

  // dt table for the 124 H=8dt steps + tails
#pragma unroll 1
  for (int idx = t; idx < 124; idx += 1024)
    dts[idx] = tarr[8 * idx + 8] - tarr[8 * idx];  // H = 8*dt
  const float dt4 = tarr[996] - tarr[992];
  const float dt2 = tarr[998] - tarr[996];
  const float dtt = tarr[999] - tarr[998];

  // z state: row q8, replicated across the 8 e8 lanes
  float zv = z0in[(size_t)n * ZZ + q8];
  if (t < 32) {
    const float4 zl = *(const float4*)(z0in + (size_t)n * ZZ + 4 * t);
    h4 pk;
    pk[0] = (_Float16)zl.x; pk[1] = (_Float16)zl.y;
    pk[2] = (_Float16)zl.z; pk[3] = (_Float16)zl.w;
    *(h4*)((char*)zp + (t >> 2) * 48 + (t & 3) * 8) = pk;
  }

  // hoisted LDS addresses (r14-proven phase-buffer patterns)
  const char* zrd = (const char*)zp + e8 * 48;
  const char* h1rd = (const char*)h1p + e8 * 80;
  const char* h2rd = (const char*)h2p + e8 * 80;
  char* h1wr = (char*)h1p + ((2 * q8) >> 5) * 80 + ((2 * q8) & 31) * 2;
  char* h2wr = (char*)h2p + ((2 * q8) >> 5) * 80 + ((2 * q8) & 31) * 2;
  _Float16* zwr = (_Float16*)((char*)zp + (q8 >> 4) * 48) + (q8 & 15);
  const int hdwr_off = ((2 * q8) >> 5) * 80 + ((2 * q8) & 31) * 2;
  const int hdrd_off = (s16 >> 1) * 80 + (s16 & 1) * 32;

  // One RK2 double-stage, no folded decode; stashes z,k1,k2,H at entry el.
  auto two_stage_ns = [&](float Hv, int el) {
#pragma unroll
    for (int st = 0; st < 2; ++st) {
      __syncthreads();  // zp (and prior-phase buffers) ready
      // ---- phase A: L1 ----
      {
        h2 cz[8];
        const uint4* zq = (const uint4*)zrd;
        uint4 u0 = zq[0], u1 = zq[1];
        u4c(u0, cz); u4c(u1, cz + 4);
        float a0 = 0.f, a1 = 0.f;
#pragma unroll
        for (int j = 0; j < 8; ++j) {
          a0 = fdot2(wL1[0][j], cz[j], a0);
          a1 = fdot2(wL1[1][j], cz[j], a1);
        }
        a0 = red8(a0);
        a1 = red8(a1);
        if (e8 == 0)
          *(h2*)h1wr = pack2(elu1(a0 + bo1r[0]), elu1(a1 + bo1r[1]));
      }
      __syncthreads();
      // ---- phase B: L2 ----
      {
        h2 ch[16];
        const uint4* hq = (const uint4*)h1rd;
        uint4 u0 = hq[0], u1 = hq[1], u2 = hq[2], u3 = hq[3];
        u4c(u0, ch); u4c(u1, ch + 4); u4c(u2, ch + 8); u4c(u3, ch + 12);
        float a0 = 0.f, a1 = 0.f;
#pragma unroll
        for (int j = 0; j < 16; ++j) {
          a0 = fdot2(wL2[0][j], ch[j], a0);
          a1 = fdot2(wL2[1][j], ch[j], a1);
        }
        a0 = red8(a0);
        a1 = red8(a1);
        if (e8 == 0)
          *(h2*)h2wr = pack2(elu1(a0 + bo2r[0]), elu1(a1 + bo2r[1]));
      }
      __syncthreads();
      // ---- phase C: L3 + RK2 update + stash ----
      {
        h2 ch[16];
        const uint4* hq = (const uint4*)h2rd;
        uint4 u0 = hq[0], u1 = hq[1], u2 = hq[2], u3 = hq[3];
        u4c(u0, ch); u4c(u1, ch + 4); u4c(u2, ch + 8); u4c(u3, ch + 12);
        float a = 0.f;
#pragma unroll
        for (int j = 0; j < 16; ++j) a = fdot2(wL3[j], ch[j], a);
        a = red8(a);
        const float f = a + bo3r;  // valid in all 8 lanes of the group
        float zc;
        if (st == 0) {
          if (e8 == 0) {
            stz[el * 128 + q8] = zv;   // z at entry start
            stk1[el * 128 + q8] = f;   // k1
          }
          if (t == 0) stH[el] = Hv;
          zc = zv + 0.5f * Hv * f;  // zmid
        } else {
          if (e8 == 0) stk2[el * 128 + q8] = f;  // k2
          zv += Hv * f;
          zc = zv;
        }
        if (e8 == 0) *zwr = (_Float16)zc;
      }
    }
  };

  // ---------------- main loop: 16 chunks of (serial + burst) -------------
#pragma unroll 1
  for (int chunk = 0; chunk < 16; ++chunk) {
    const int e0 = 8 * chunk;
#pragma unroll 1
    for (int e = e0; e < e0 + 8; ++e) {
      const int el = e & 7;
      if (e < 124) {
        two_stage_ns(dts[e], el);
      } else if (e == 124) {
        two_stage_ns(dt4, el);
      } else if (e == 125) {
        two_stage_ns(dt2, el);
      } else if (e == 126) {
        two_stage_ns(dtt, el);
      } else {  // 127: stash final z; zero k's so th=0 reads are safe
        if (e8 == 0) {
          stz[el * 128 + q8] = zv;
          stk1[el * 128 + q8] = 0.f;
          stk2[el * 128 + q8] = 0.f;
        }
        if (t == 0) stH[el] = 0.f;
      }
    }
    __syncthreads();  // stash complete
    const int p0 = 64 * chunk;
    const int P = (1000 - p0 < 64) ? (1000 - p0) : 64;
    // ---- phase ZEST: quadratic dense-output estimates (f32 -> f16) ----
#pragma unroll 1
    for (int idx = t; idx < P * 64; idx += 1024) {
      const int lp = idx >> 6, pr = idx & 63;
      const int p = p0 + lp;
      int e;
      float th;
      if (p < 992) {
        e = p >> 3;
        th = (float)(p & 7) * 0.125f;
      } else if (p < 996) {
        e = 124;
        th = (float)(p - 992) * 0.25f;
      } else if (p < 998) {
        e = 125;
        th = (float)(p - 996) * 0.5f;
      } else if (p == 998) {
        e = 126;
        th = 0.f;
      } else {
        e = 127;
        th = 0.f;
      }
      const int el = e & 7;
      const float Hv = stH[el];
      const float k10 = stk1[el * 128 + 2 * pr];
      const float k11 = stk1[el * 128 + 2 * pr + 1];
      const float k20 = stk2[el * 128 + 2 * pr];
      const float k21 = stk2[el * 128 + 2 * pr + 1];
      float z0 = stz[el * 128 + 2 * pr];
      float z1 = stz[el * 128 + 2 * pr + 1];
      z0 += Hv * (th * k10 + th * th * (k20 - k10));
      z1 += Hv * (th * k11 + th * th * (k21 - k11));
      *(h2*)(zest + lp * 128 + 2 * pr) = pack2(z0, z1);
    }
    __syncthreads();
    // ---- phase D1-burst: all positions, back-to-back ----
#pragma unroll 1
    for (int lp = 0; lp < P; ++lp) {
      h2 cz[8];
      const uint4* zq = (const uint4*)((char*)zest + lp * 256 + e8 * 32);
      uint4 u0 = zq[0], u1 = zq[1];
      u4c(u0, cz); u4c(u1, cz + 4);
      float a0 = 0.f, a1 = 0.f;
#pragma unroll
      for (int j = 0; j < 8; ++j) {
        a0 = fdot2(wD1[0][j], cz[j], a0);
        a1 = fdot2(wD1[1][j], cz[j], a1);
      }
      a0 = red8(a0);
      a1 = red8(a1);
      if (e8 == 0) {
        float v0 = a0 + bd1r[0], v1 = a1 + bd1r[1];
        v0 = v0 > 0.f ? v0 : 0.f;
        v1 = v1 > 0.f ? v1 : 0.f;
        *(h2*)(hdb + lp * 640 + hdwr_off) = pack2(v0, v1);
      }
    }
    __syncthreads();
    // ---- phase D2-burst: all positions -> f32 out (proven path) ----
#pragma unroll 1
    for (int lp = 0; lp < P; ++lp) {
      h2 hh[8];
      const uint4* ph = (const uint4*)(hdb + lp * 640 + hdrd_off);
      uint4 u0 = ph[0], u1 = ph[1];
      u4c(u0, hh); u4c(u1, hh + 4);
      float a = 0.f;
#pragma unroll
      for (int j = 0; j < 8; ++j) a = fdot2(wD2[j], hh[j], a);
      a = red16(a);
      if (s16 == 0)
        out[((size_t)n * SS + (p0 + lp)) * DD + g16] = a + bd2r;
    }
    __syncthreads();  // hdb/zest/stash reusable by next chunk
  }
}

extern "C" void kernel_launch(void* const* d_in, const int* in_sizes, int n_in,
                              void* d_out, int out_size, void* d_ws,
                              size_t ws_size, hipStream_t stream) {
  const float* X = (const float*)d_in[0];
  const float* tarr = (const float*)d_in[1];
  const float* eps = (const float*)d_in[2];
  const float* Wih = (const float*)d_in[3];
  const float* Whh = (const float*)d_in[4];
  const float* bih = (const float*)d_in[5];
  const float* bhh = (const float*)d_in[6];
  const float* Wcomp = (const float*)d_in[7];
  const float* bcomp = (const float*)d_in[8];
  const float* Wrc = (const float*)d_in[9];
  const float* brc = (const float*)d_in[10];
  const float* Wo1 = (const float*)d_in[11];
  const float* bo1 = (const float*)d_in[12];
  const float* Wo2 = (const float*)d_in[13];
  const float* bo2 = (const float*)d_in[14];
  const float* Wo3 = (const float*)d_in[15];
  const float* bo3 = (const float*)d_in[16];
  const float* Wd1 = (const float*)d_in[17];
  const float* bd1 = (const float*)d_in[18];
  const float* Wd2 = (const float*)d_in[19];
  const float* bd2 = (const float*)d_in[20];
  float* out = (float*)d_out;
  float* z0ws = (float*)d_ws;  // 256*128 f32 = 128 KiB

  k_rnn<<<dim3(NN), dim3(512), 0, stream>>>(X, Wih, Whh, bih, bhh, Wcomp,
                                            bcomp, eps, Wrc, brc, z0ws);
  k_ode<<<dim3(NN), dim3(1024), SMEM_BYTES, stream>>>(
      tarr, z0ws, Wo1, bo1, Wo2, bo2, Wo3, bo3, Wd1, bd1, Wd2, bd2, out);
}

// Round 19
// 1395.435 us; speedup vs baseline: 1.4110x; 1.1092x over previous
//
#include <hip/hip_runtime.h>

typedef _Float16 h2 __attribute__((ext_vector_type(2)));
typedef _Float16 h4 __attribute__((ext_vector_type(4)));

#define NN 256
#define SS 1000
#define DD 64
#define HH 256
#define ZZ 128
#define HIDN 256

__device__ __forceinline__ float fdot2(h2 a, h2 b, float c) {
  return __builtin_amdgcn_fdot2(a, b, c, false);
}
__device__ __forceinline__ float fast_tanh(float x) {
  float e = __expf(2.0f * x);
  return 1.0f - 2.0f / (e + 1.0f);
}
__device__ __forceinline__ float elu1(float x) {
  return x > 0.0f ? x : (__expf(x) - 1.0f);
}
__device__ __forceinline__ h2 pack2(float a, float b) {
  h2 r; r.x = (_Float16)a; r.y = (_Float16)b; return r;
}
__device__ __forceinline__ void u4c(uint4 u, h2* c) {
  c[0] = __builtin_bit_cast(h2, u.x);
  c[1] = __builtin_bit_cast(h2, u.y);
  c[2] = __builtin_bit_cast(h2, u.z);
  c[3] = __builtin_bit_cast(h2, u.w);
}
// DPP cross-lane adds (numerics proven identical to shfl_xor in r5/r6).
template <int CTRL>
__device__ __forceinline__ float dppadd(float a) {
  int x = __builtin_bit_cast(int, a);
  int y = __builtin_amdgcn_update_dpp(0, x, CTRL, 0xf, 0xf, true);
  return a + __builtin_bit_cast(float, y);
}
__device__ __forceinline__ float red4(float a) {
  a = dppadd<0xB1>(a); a = dppadd<0x4E>(a); return a;
}
__device__ __forceinline__ float red8(float a) {
  a = dppadd<0x141>(a); a = dppadd<0x4E>(a); a = dppadd<0xB1>(a); return a;
}
__device__ __forceinline__ float red16(float a) {
  a = dppadd<0x140>(a); a = dppadd<0x141>(a); a = dppadd<0x4E>(a);
  a = dppadd<0xB1>(a); return a;
}

// ---------------- Kernel 1: reverse RNN + encoder -> z0 ----------------
// (byte-identical to the passing round-18 version)
__global__ __launch_bounds__(512, 2) void k_rnn(
    const float* __restrict__ X, const float* __restrict__ Wih,
    const float* __restrict__ Whh, const float* __restrict__ bih,
    const float* __restrict__ bhh, const float* __restrict__ Wcomp,
    const float* __restrict__ bcomp, const float* __restrict__ eps,
    const float* __restrict__ Wrc, const float* __restrict__ brc,
    float* __restrict__ z0out) {
  const int n = blockIdx.x;
  const int t = threadIdx.x;
  const int g = t >> 2, c = t & 3;
  __shared__ __align__(16) _Float16 hb[2][HH];       // contiguous h state
  __shared__ __align__(16) _Float16 xc[2][16][DD];   // 2 x 16-step x chunks
  __shared__ float comp_s[HH];
  __shared__ float zenc_s[ZZ];

  h2 wih2[2][8];   // rows {2g,2g+1} x cols 16c..16c+15
  h2 whh2[2][32];  // rows {2g,2g+1} x cols 64c..64c+63
  float bi2[2];
#pragma unroll
  for (int i = 0; i < 2; ++i) {
    const float4* wp = (const float4*)(Wih + (2 * g + i) * DD + 16 * c);
#pragma unroll
    for (int j4 = 0; j4 < 4; ++j4) {
      float4 v = wp[j4];
      wih2[i][2 * j4] = pack2(v.x, v.y);
      wih2[i][2 * j4 + 1] = pack2(v.z, v.w);
    }
    const float4* hp = (const float4*)(Whh + (2 * g + i) * HH + 64 * c);
#pragma unroll
    for (int j4 = 0; j4 < 16; ++j4) {
      float4 v = hp[j4];
      whh2[i][2 * j4] = pack2(v.x, v.y);
      whh2[i][2 * j4 + 1] = pack2(v.z, v.w);
    }
    bi2[i] = bih[2 * g + i] + bhh[2 * g + i];
  }
  // stage chunk cn (steps 16cn..16cn+15): 512 thr x float2 = 16 rows x 64
  auto stage = [&](int cn) {
    const int row = t >> 5;          // 0..15
    const int sp = 16 * cn + row;    // step index
    if (sp < SS) {
      const float2 v =
          ((const float2*)(X + ((size_t)n * SS + (SS - 1 - sp)) * DD))[t & 31];
      *(h2*)(&xc[cn & 1][row][(t & 31) * 2]) = pack2(v.x, v.y);
    }
  };
  if (t < HH) hb[0][t] = (_Float16)0.0f;
  stage(0);
  int cur = 0;
#pragma unroll 1
  for (int s = 0; s < SS; ++s) {
    __syncthreads();  // xc chunk, hb[cur] ready
    if ((s & 15) == 0) {
      const int cn = (s >> 4) + 1;
      if (16 * cn < SS) stage(cn);  // prefetch next chunk (other buffer)
    }
    h2 cx[8];   // x quarter: 16 f16
    h2 ch[32];  // h quarter: 64 f16
    {
      const uint4* xq = (const uint4*)(&xc[(s >> 4) & 1][s & 15][16 * c]);
      u4c(xq[0], cx);
      u4c(xq[1], cx + 4);
      const uint4* hq = (const uint4*)(hb[cur] + 64 * c);
#pragma unroll
      for (int j4 = 0; j4 < 8; ++j4) u4c(hq[j4], ch + 4 * j4);
    }
    float a0 = 0.f, a1 = 0.f;
#pragma unroll
    for (int j = 0; j < 8; ++j) {
      a0 = fdot2(wih2[0][j], cx[j], a0);
      a1 = fdot2(wih2[1][j], cx[j], a1);
    }
#pragma unroll
    for (int j = 0; j < 32; ++j) {
      a0 = fdot2(whh2[0][j], ch[j], a0);
      a1 = fdot2(whh2[1][j], ch[j], a1);
    }
    a0 = red4(a0);
    a1 = red4(a1);
    if (c == 0)
      ((h2*)hb[cur ^ 1])[g] =
          pack2(fast_tanh(a0 + bi2[0]), fast_tanh(a1 + bi2[1]));
    cur ^= 1;
  }
  __syncthreads();
  // ---- encoder epilogue (one-time) ----
  const int r2 = t >> 1, c2 = t & 1;
  {
    float a = c2 ? 0.0f : bcomp[r2];
    const float4* wc = (const float4*)(Wcomp + r2 * HH + c2 * 128);
#pragma unroll 8
    for (int j = 0; j < 32; ++j) {
      float4 w = wc[j];
      a += w.x * (float)hb[cur][c2 * 128 + 4 * j + 0] +
           w.y * (float)hb[cur][c2 * 128 + 4 * j + 1] +
           w.z * (float)hb[cur][c2 * 128 + 4 * j + 2] +
           w.w * (float)hb[cur][c2 * 128 + 4 * j + 3];
    }
    a += __shfl_xor(a, 1);
    if (!c2) comp_s[r2] = a;
  }
  __syncthreads();
  if (t < ZZ) {
    float mu = comp_s[t];
    float sd = comp_s[t + ZZ];
    zenc_s[t] = eps[(size_t)n * ZZ + t] * sd + mu;
  }
  __syncthreads();
  {
    const int r4 = t >> 2, c4 = t & 3;
    float a = c4 ? 0.0f : brc[r4];
    const float4* wr = (const float4*)(Wrc + r4 * ZZ + c4 * 32);
    const float* zl = zenc_s + c4 * 32;
#pragma unroll
    for (int j = 0; j < 8; ++j) {
      float4 w = wr[j];
      a += w.x * zl[4 * j + 0] + w.y * zl[4 * j + 1] + w.z * zl[4 * j + 2] +
           w.w * zl[4 * j + 3];
    }
    a += __shfl_xor(a, 1);
    a += __shfl_xor(a, 2);
    if (!c4) z0out[(size_t)n * ZZ + r4] = a;
  }
}

// ------- Kernel 2: ODE, RK2 H=16dt + quadratic dense output --------------
// 66 stash entries: e=0..61 H=16dt steps (0->992), 62 (H=4dt, 992->996),
// 63 (H=2dt, 996->998), 64 (H=dt, 998->999), 65 final-z. Chunks 0-14 use
// 4 entries (64 positions each); chunk 15 uses 6 entries (pos 960-999).
// Dense output: q(th) = z + H*(th*k1 + th^2*(k2-k1)) — decode-only O(H^3).
//   p<992: e=p>>4, th=(p&15)/16; 992-995: e=62, th=(p-992)/4;
//   996-997: e=63, th=(p-996)/2; 998: e=64, th=0; 999: e=65, th=0.
#define OFF_STZ 0        // 8 x 128 f32 = 4096
#define OFF_STK1 4096    // 4096
#define OFF_STK2 8192    // 4096
#define OFF_STH 12288    // 8 f32 -> 64
#define OFF_DTS 12352    // 62 f32 -> 512
#define OFF_ZP 12864     // 8 x 48B = 384
#define OFF_H1P 13248    // 8 x 80B = 640
#define OFF_H2P 13888    // 8 x 80B = 640
#define OFF_ZEST 14528   // 64 x 256B = 16384
#define OFF_HDB 30912    // 64 x 640B = 40960
#define SMEM_BYTES 71872

__global__ __launch_bounds__(1024, 1) void k_ode(
    const float* __restrict__ tarr, const float* __restrict__ z0in,
    const float* __restrict__ Wo1, const float* __restrict__ bo1p,
    const float* __restrict__ Wo2, const float* __restrict__ bo2p,
    const float* __restrict__ Wo3, const float* __restrict__ bo3p,
    const float* __restrict__ Wd1, const float* __restrict__ bd1p,
    const float* __restrict__ Wd2, const float* __restrict__ bd2p,
    float* __restrict__ out) {
  extern __shared__ char smem[];
  float* stz = (float*)(smem + OFF_STZ);    // [8][128]
  float* stk1 = (float*)(smem + OFF_STK1);  // [8][128]
  float* stk2 = (float*)(smem + OFF_STK2);  // [8][128]
  float* stH = (float*)(smem + OFF_STH);    // [8]
  float* dts = (float*)(smem + OFF_DTS);
  _Float16* zp = (_Float16*)(smem + OFF_ZP);
  _Float16* h1p = (_Float16*)(smem + OFF_H1P);
  _Float16* h2p = (_Float16*)(smem + OFF_H2P);
  _Float16* zest = (_Float16*)(smem + OFF_ZEST);  // [64][128]
  char* hdb = smem + OFF_HDB;                     // [64][640B]

  const int n = blockIdx.x;
  const int t = threadIdx.x;
  const int q8 = t >> 3, e8 = t & 7;
  const int g16 = t >> 4, s16 = t & 15;

  h2 wL1[2][8];   // Wo1 rows {2q8,2q8+1} x cols 16e8..16e8+15
  h2 wL2[2][16];  // Wo2 rows {2q8,2q8+1} x cols 32e8..32e8+31
  h2 wL3[16];     // Wo3 row q8 x cols 32e8..32e8+31
  h2 wD1[2][8];   // Wd1 rows {2q8,2q8+1} x cols 16e8..16e8+15 (registers)
  h2 wD2[8];      // Wd2 row g16 x cols 16s16..16s16+15 (registers)
  float bo1r[2], bo2r[2], bd1r[2];
#pragma unroll
  for (int i = 0; i < 2; ++i) {
    const float4* p1 = (const float4*)(Wo1 + (2 * q8 + i) * ZZ + 16 * e8);
#pragma unroll
    for (int j4 = 0; j4 < 4; ++j4) {
      float4 v = p1[j4];
      wL1[i][2 * j4] = pack2(v.x, v.y);
      wL1[i][2 * j4 + 1] = pack2(v.z, v.w);
    }
    const float4* p2 = (const float4*)(Wo2 + (2 * q8 + i) * HIDN + 32 * e8);
#pragma unroll
    for (int j4 = 0; j4 < 8; ++j4) {
      float4 v = p2[j4];
      wL2[i][2 * j4] = pack2(v.x, v.y);
      wL2[i][2 * j4 + 1] = pack2(v.z, v.w);
    }
    const float4* pd = (const float4*)(Wd1 + (2 * q8 + i) * ZZ + 16 * e8);
#pragma unroll
    for (int j4 = 0; j4 < 4; ++j4) {
      float4 v = pd[j4];
      wD1[i][2 * j4] = pack2(v.x, v.y);
      wD1[i][2 * j4 + 1] = pack2(v.z, v.w);
    }
    bo1r[i] = bo1p[2 * q8 + i];
    bo2r[i] = bo2p[2 * q8 + i];
    bd1r[i] = bd1p[2 * q8 + i];
  }
  {
    const float4* p3 = (const float4*)(Wo3 + q8 * HIDN + 32 * e8);
#pragma unroll
    for (int j4 = 0; j4 < 8; ++j4) {
      float4 v = p3[j4];
      wL3[2 * j4] = pack2(v.x, v.y);
      wL3[2 * j4 + 1] = pack2(v.z, v.w);
    }
    const float4* pd2 = (const float4*)(Wd2 + g16 * HIDN + 16 * s16);
#pragma unroll
    for (int j4 = 0; j4 < 4; ++j4) {
      float4 v = pd2[j4];
      wD2[2 * j4] = pack2(v.x, v.y);
      wD2[2 * j4 + 1] = pack2(v.z, v.w);
    }
  }
  const float bo3r = bo3p[q8];
  const float bd2r = bd2p[g16];

  // dt table for the 62 H=16dt steps + tails
#pragma unroll 1
  for (int idx = t; idx < 62; idx += 1024)
    dts[idx] = tarr[16 * idx + 16] - tarr[16 * idx];  // H = 16*dt
  const float dt4 = tarr[996] - tarr[992];
  const float dt2 = tarr[998] - tarr[996];
  const float dtt = tarr[999] - tarr[998];

  // z state: row q8, replicated across the 8 e8 lanes
  float zv = z0in[(size_t)n * ZZ + q8];
  if (t < 32) {
    const float4 zl = *(const float4*)(z0in + (size_t)n * ZZ + 4 * t);
    h4 pk;
    pk[0] = (_Float16)zl.x; pk[1] = (_Float16)zl.y;
    pk[2] = (_Float16)zl.z; pk[3] = (_Float16)zl.w;
    *(h4*)((char*)zp + (t >> 2) * 48 + (t & 3) * 8) = pk;
  }

  // hoisted LDS addresses (r14-proven phase-buffer patterns)
  const char* zrd = (const char*)zp + e8 * 48;
  const char* h1rd = (const char*)h1p + e8 * 80;
  const char* h2rd = (const char*)h2p + e8 * 80;
  char* h1wr = (char*)h1p + ((2 * q8) >> 5) * 80 + ((2 * q8) & 31) * 2;
  char* h2wr = (char*)h2p + ((2 * q8) >> 5) * 80 + ((2 * q8) & 31) * 2;
  _Float16* zwr = (_Float16*)((char*)zp + (q8 >> 4) * 48) + (q8 & 15);
  const int hdwr_off = ((2 * q8) >> 5) * 80 + ((2 * q8) & 31) * 2;
  const int hdrd_off = (s16 >> 1) * 80 + (s16 & 1) * 32;

  // One RK2 double-stage, no folded decode; stashes z,k1,k2,H at entry el.
  auto two_stage_ns = [&](float Hv, int el) {
#pragma unroll
    for (int st = 0; st < 2; ++st) {
      __syncthreads();  // zp (and prior-phase buffers) ready
      // ---- phase A: L1 ----
      {
        h2 cz[8];
        const uint4* zq = (const uint4*)zrd;
        uint4 u0 = zq[0], u1 = zq[1];
        u4c(u0, cz); u4c(u1, cz + 4);
        float a0 = 0.f, a1 = 0.f;
#pragma unroll
        for (int j = 0; j < 8; ++j) {
          a0 = fdot2(wL1[0][j], cz[j], a0);
          a1 = fdot2(wL1[1][j], cz[j], a1);
        }
        a0 = red8(a0);
        a1 = red8(a1);
        if (e8 == 0)
          *(h2*)h1wr = pack2(elu1(a0 + bo1r[0]), elu1(a1 + bo1r[1]));
      }
      __syncthreads();
      // ---- phase B: L2 ----
      {
        h2 ch[16];
        const uint4* hq = (const uint4*)h1rd;
        uint4 u0 = hq[0], u1 = hq[1], u2 = hq[2], u3 = hq[3];
        u4c(u0, ch); u4c(u1, ch + 4); u4c(u2, ch + 8); u4c(u3, ch + 12);
        float a0 = 0.f, a1 = 0.f;
#pragma unroll
        for (int j = 0; j < 16; ++j) {
          a0 = fdot2(wL2[0][j], ch[j], a0);
          a1 = fdot2(wL2[1][j], ch[j], a1);
        }
        a0 = red8(a0);
        a1 = red8(a1);
        if (e8 == 0)
          *(h2*)h2wr = pack2(elu1(a0 + bo2r[0]), elu1(a1 + bo2r[1]));
      }
      __syncthreads();
      // ---- phase C: L3 + RK2 update + stash ----
      {
        h2 ch[16];
        const uint4* hq = (const uint4*)h2rd;
        uint4 u0 = hq[0], u1 = hq[1], u2 = hq[2], u3 = hq[3];
        u4c(u0, ch); u4c(u1, ch + 4); u4c(u2, ch + 8); u4c(u3, ch + 12);
        float a = 0.f;
#pragma unroll
        for (int j = 0; j < 16; ++j) a = fdot2(wL3[j], ch[j], a);
        a = red8(a);
        const float f = a + bo3r;  // valid in all 8 lanes of the group
        float zc;
        if (st == 0) {
          if (e8 == 0) {
            stz[el * 128 + q8] = zv;   // z at entry start
            stk1[el * 128 + q8] = f;   // k1
          }
          if (t == 0) stH[el] = Hv;
          zc = zv + 0.5f * Hv * f;  // zmid
        } else {
          if (e8 == 0) stk2[el * 128 + q8] = f;  // k2
          zv += Hv * f;
          zc = zv;
        }
        if (e8 == 0) *zwr = (_Float16)zc;
      }
    }
  };

  // ---------------- main loop: 16 chunks of (serial + burst) -------------
#pragma unroll 1
  for (int chunk = 0; chunk < 16; ++chunk) {
    const int e_begin = (chunk < 15) ? 4 * chunk : 60;
    const int e_end = (chunk < 15) ? 4 * chunk + 4 : 66;
#pragma unroll 1
    for (int e = e_begin; e < e_end; ++e) {
      const int el = e - e_begin;
      if (e < 62) {
        two_stage_ns(dts[e], el);
      } else if (e == 62) {
        two_stage_ns(dt4, el);
      } else if (e == 63) {
        two_stage_ns(dt2, el);
      } else if (e == 64) {
        two_stage_ns(dtt, el);
      } else {  // 65: stash final z; zero k's so th=0 reads are safe
        if (e8 == 0) {
          stz[el * 128 + q8] = zv;
          stk1[el * 128 + q8] = 0.f;
          stk2[el * 128 + q8] = 0.f;
        }
        if (t == 0) stH[el] = 0.f;
      }
    }
    __syncthreads();  // stash complete
    const int p0 = 64 * chunk;
    const int P = (1000 - p0 < 64) ? (1000 - p0) : 64;
    // ---- phase ZEST: quadratic dense-output estimates (f32 -> f16) ----
#pragma unroll 1
    for (int idx = t; idx < P * 64; idx += 1024) {
      const int lp = idx >> 6, pr = idx & 63;
      const int p = p0 + lp;
      int e;
      float th;
      if (p < 992) {
        e = p >> 4;
        th = (float)(p & 15) * 0.0625f;
      } else if (p < 996) {
        e = 62;
        th = (float)(p - 992) * 0.25f;
      } else if (p < 998) {
        e = 63;
        th = (float)(p - 996) * 0.5f;
      } else if (p == 998) {
        e = 64;
        th = 0.f;
      } else {
        e = 65;
        th = 0.f;
      }
      const int el = e - e_begin;
      const float Hv = stH[el];
      const float k10 = stk1[el * 128 + 2 * pr];
      const float k11 = stk1[el * 128 + 2 * pr + 1];
      const float k20 = stk2[el * 128 + 2 * pr];
      const float k21 = stk2[el * 128 + 2 * pr + 1];
      float z0 = stz[el * 128 + 2 * pr];
      float z1 = stz[el * 128 + 2 * pr + 1];
      z0 += Hv * (th * k10 + th * th * (k20 - k10));
      z1 += Hv * (th * k11 + th * th * (k21 - k11));
      *(h2*)(zest + lp * 128 + 2 * pr) = pack2(z0, z1);
    }
    __syncthreads();
    // ---- phase D1-burst: all positions, back-to-back ----
#pragma unroll 1
    for (int lp = 0; lp < P; ++lp) {
      h2 cz[8];
      const uint4* zq = (const uint4*)((char*)zest + lp * 256 + e8 * 32);
      uint4 u0 = zq[0], u1 = zq[1];
      u4c(u0, cz); u4c(u1, cz + 4);
      float a0 = 0.f, a1 = 0.f;
#pragma unroll
      for (int j = 0; j < 8; ++j) {
        a0 = fdot2(wD1[0][j], cz[j], a0);
        a1 = fdot2(wD1[1][j], cz[j], a1);
      }
      a0 = red8(a0);
      a1 = red8(a1);
      if (e8 == 0) {
        float v0 = a0 + bd1r[0], v1 = a1 + bd1r[1];
        v0 = v0 > 0.f ? v0 : 0.f;
        v1 = v1 > 0.f ? v1 : 0.f;
        *(h2*)(hdb + lp * 640 + hdwr_off) = pack2(v0, v1);
      }
    }
    __syncthreads();
    // ---- phase D2-burst: all positions -> f32 out (proven path) ----
#pragma unroll 1
    for (int lp = 0; lp < P; ++lp) {
      h2 hh[8];
      const uint4* ph = (const uint4*)(hdb + lp * 640 + hdrd_off);
      uint4 u0 = ph[0], u1 = ph[1];
      u4c(u0, hh); u4c(u1, hh + 4);
      float a = 0.f;
#pragma unroll
      for (int j = 0; j < 8; ++j) a = fdot2(wD2[j], hh[j], a);
      a = red16(a);
      if (s16 == 0)
        out[((size_t)n * SS + (p0 + lp)) * DD + g16] = a + bd2r;
    }
    __syncthreads();  // hdb/zest/stash reusable by next chunk
  }
}

extern "C" void kernel_launch(void* const* d_in, const int* in_sizes, int n_in,
                              void* d_out, int out_size, void* d_ws,
                              size_t ws_size, hipStream_t stream) {
  const float* X = (const float*)d_in[0];
  const float* tarr = (const float*)d_in[1];
  const float* eps = (const float*)d_in[2];
  const float* Wih = (const float*)d_in[3];
  const float* Whh = (const float*)d_in[4];
  const float* bih = (const float*)d_in[5];
  const float* bhh = (const float*)d_in[6];
  const float* Wcomp = (const float*)d_in[7];
  const float* bcomp = (const float*)d_in[8];
  const float* Wrc = (const float*)d_in[9];
  const float* brc = (const float*)d_in[10];
  const float* Wo1 = (const float*)d_in[11];
  const float* bo1 = (const float*)d_in[12];
  const float* Wo2 = (const float*)d_in[13];
  const float* bo2 = (const float*)d_in[14];
  const float* Wo3 = (const float*)d_in[15];
  const float* bo3 = (const float*)d_in[16];
  const float* Wd1 = (const float*)d_in[17];
  const float* bd1 = (const float*)d_in[18];
  const float* Wd2 = (const float*)d_in[19];
  const float* bd2 = (const float*)d_in[20];
  float* out = (float*)d_out;
  float* z0ws = (float*)d_ws;  // 256*128 f32 = 128 KiB

  k_rnn<<<dim3(NN), dim3(512), 0, stream>>>(X, Wih, Whh, bih, bhh, Wcomp,
                                            bcomp, eps, Wrc, brc, z0ws);
  k_ode<<<dim3(NN), dim3(1024), SMEM_BYTES, stream>>>(
      tarr, z0ws, Wo1, bo1, Wo2, bo2, Wo3, bo3, Wd1, bd1, Wd2, bd2, out);
}